// Round 3
// baseline (979.111 us; speedup 1.0000x reference)
//
#include <hip/hip_runtime.h>
#include <hip/hip_bf16.h>

#define NN 4096
#define IC 128
#define OC 128
#define ED 16
#define EPB 128
#define NT 256

// Phase 1: xw1b[n][c] = b1[c] + sum_k x[n][k] * W1[k][c]   (row-only part of layer 1)
__global__ __launch_bounds__(128) void k_xw1(
    const float* __restrict__ x, const float* __restrict__ W1,
    const float* __restrict__ b1, float* __restrict__ xw1b)
{
    __shared__ float xs[8][IC];
    const int t = threadIdx.x;
    const int r0 = blockIdx.x * 8;
    #pragma unroll
    for (int r = 0; r < 8; ++r) xs[r][t] = x[(size_t)(r0 + r) * IC + t];
    __syncthreads();
    float acc[8];
    const float bb = b1[t];
    #pragma unroll
    for (int r = 0; r < 8; ++r) acc[r] = bb;
    #pragma unroll 4
    for (int k = 0; k < IC; ++k) {
        const float w = W1[(size_t)k * OC + t];
        #pragma unroll
        for (int r = 0; r < 8; ++r) acc[r] = fmaf(xs[r][k], w, acc[r]);
    }
    #pragma unroll
    for (int r = 0; r < 8; ++r) xw1b[(size_t)(r0 + r) * OC + t] = acc[r];
}

// Phase 2: batched. Per block: 128 edges.
//   stage W2 (64KB) + W1e (8KB) in LDS; gather ea + xw1b[row] (regs);
//   layer1 -> h1s LDS (64KB, XOR-swizzled); layer2 as register-tiled GEMM
//   (8e x 8c per thread, 16 FMA per ds_read_b128); atomicAdd scatter by col.
// LDS swizzle: f4index ^ ((e>>3)&3) breaks the 512B-row-stride bank aliasing
// across the 4 edge-groups of a wave (G4: rows differing by 8 share banks).
__global__ __launch_bounds__(NT, 1) void k_edge2(
    const int* __restrict__ eidx, const float* __restrict__ eattr,
    const float* __restrict__ xw1b, const float* __restrict__ W1,
    const float* __restrict__ W2, const float* __restrict__ b2,
    float* __restrict__ out, int E)
{
    extern __shared__ char smem[];
    float4* const W2L  = (float4*)smem;      // [128][32] f4 = 64KB, linear
    float4* const h1s  = W2L + 4096;         // [128][32] f4 = 64KB, swizzled
    float4* const eaL  = h1s + 4096;         // [128][4]  f4 =  8KB, swizzled
    float4* const w1L  = eaL + 512;          // [16][32]  f4 =  8KB, linear
    int*    const srowL = (int*)(w1L + 512); // [128]
    int*    const scolL = srowL + EPB;       // [128]

    const int t  = threadIdx.x;
    const int cg = t & 15;            // c0 = 8*cg
    const int eg = t >> 4;            // e0 = 8*eg
    const int c0 = cg << 3;
    const int e0 = eg << 3;
    const int sz = eg & 3;            // swizzle key for rows e0..e0+7

    const int e0blk = blockIdx.x * EPB;
    const int nedge = min(EPB, E - e0blk);
    if (nedge <= 0) return;

    // ---- stage: indices, W2, W1e, b2 ----
    int myidx = 0;
    if (t < EPB) { if (t < nedge) myidx = eidx[e0blk + t]; }
    else         { if (t - EPB < nedge) myidx = eidx[E + e0blk + (t - EPB)]; }

    const float4* W2v = (const float4*)W2;
    #pragma unroll
    for (int i = 0; i < 16; ++i) W2L[t + NT * i] = W2v[t + NT * i];
    const float4* W1v = (const float4*)(W1 + (size_t)IC * OC);
    w1L[t]      = W1v[t];
    w1L[t + NT] = W1v[t + NT];
    const float4* b2v = (const float4*)b2;
    const float4 b2a = b2v[cg * 2], b2b = b2v[cg * 2 + 1];

    if (t < EPB) srowL[t] = myidx; else scolL[t - EPB] = myidx;
    __syncthreads();

    // ---- gather: ea (edge t>>1, half t&1) and xw1b rows ----
    const int em = t >> 1, half = t & 1;
    float4 eA = make_float4(0.f, 0.f, 0.f, 0.f), eB = eA;
    if (em < nedge) {
        const float4* p = (const float4*)(eattr +
            ((size_t)srowL[em] * NN + scolL[em]) * ED);
        eA = p[half * 2]; eB = p[half * 2 + 1];
    }
    float4 xa[8], xb[8];
    #pragma unroll
    for (int ri = 0; ri < 8; ++ri) {
        const int e = e0 + ri;
        float4 za = make_float4(0.f, 0.f, 0.f, 0.f), zb = za;
        if (e < nedge) {
            const float4* p = (const float4*)(xw1b + (size_t)srowL[e] * OC + c0);
            za = p[0]; zb = p[1];
        }
        xa[ri] = za; xb[ri] = zb;
    }
    const int esz = (em >> 3) & 3;
    eaL[(em * 4 + half * 2)     ^ esz] = eA;
    eaL[(em * 4 + half * 2 + 1) ^ esz] = eB;
    __syncthreads();

    // ---- layer 1: h1[e0..e0+7][c0..c0+7] ----
    float4 ha[8], hb[8];
    #pragma unroll
    for (int ri = 0; ri < 8; ++ri) { ha[ri] = xa[ri]; hb[ri] = xb[ri]; }
    #pragma unroll
    for (int dc = 0; dc < 4; ++dc) {
        float4 ev[8];
        #pragma unroll
        for (int ri = 0; ri < 8; ++ri)
            ev[ri] = eaL[((e0 + ri) * 4 + dc) ^ sz];
        #pragma unroll
        for (int dd = 0; dd < 4; ++dd) {
            const int d = dc * 4 + dd;
            const float4 wA = w1L[d * 32 + cg * 2];
            const float4 wB = w1L[d * 32 + cg * 2 + 1];
            #pragma unroll
            for (int ri = 0; ri < 8; ++ri) {
                const float evd = (dd == 0) ? ev[ri].x : (dd == 1) ? ev[ri].y
                                 : (dd == 2) ? ev[ri].z : ev[ri].w;
                ha[ri].x = fmaf(evd, wA.x, ha[ri].x);
                ha[ri].y = fmaf(evd, wA.y, ha[ri].y);
                ha[ri].z = fmaf(evd, wA.z, ha[ri].z);
                ha[ri].w = fmaf(evd, wA.w, ha[ri].w);
                hb[ri].x = fmaf(evd, wB.x, hb[ri].x);
                hb[ri].y = fmaf(evd, wB.y, hb[ri].y);
                hb[ri].z = fmaf(evd, wB.z, hb[ri].z);
                hb[ri].w = fmaf(evd, wB.w, hb[ri].w);
            }
        }
    }
    #pragma unroll
    for (int ri = 0; ri < 8; ++ri) {
        float4 va = ha[ri], vb = hb[ri];
        va.x = fmaxf(va.x, 0.f); va.y = fmaxf(va.y, 0.f);
        va.z = fmaxf(va.z, 0.f); va.w = fmaxf(va.w, 0.f);
        vb.x = fmaxf(vb.x, 0.f); vb.y = fmaxf(vb.y, 0.f);
        vb.z = fmaxf(vb.z, 0.f); vb.w = fmaxf(vb.w, 0.f);
        h1s[((e0 + ri) * 32 + cg * 2)     ^ sz] = va;
        h1s[((e0 + ri) * 32 + cg * 2 + 1) ^ sz] = vb;
    }
    __syncthreads();

    // ---- layer 2: register-tiled GEMM, 8e x 8c per thread ----
    float4 accA[8], accB[8];
    #pragma unroll
    for (int ri = 0; ri < 8; ++ri) {
        accA[ri] = make_float4(0.f, 0.f, 0.f, 0.f);
        accB[ri] = accA[ri];
    }
    for (int k4 = 0; k4 < 32; ++k4) {
        float4 hv[8];
        #pragma unroll
        for (int ri = 0; ri < 8; ++ri)
            hv[ri] = h1s[((e0 + ri) * 32 + k4) ^ sz];
        #pragma unroll
        for (int kk = 0; kk < 4; ++kk) {
            const float4 wA = W2L[(k4 * 4 + kk) * 32 + cg * 2];
            const float4 wB = W2L[(k4 * 4 + kk) * 32 + cg * 2 + 1];
            #pragma unroll
            for (int ri = 0; ri < 8; ++ri) {
                const float h = (kk == 0) ? hv[ri].x : (kk == 1) ? hv[ri].y
                               : (kk == 2) ? hv[ri].z : hv[ri].w;
                accA[ri].x = fmaf(h, wA.x, accA[ri].x);
                accA[ri].y = fmaf(h, wA.y, accA[ri].y);
                accA[ri].z = fmaf(h, wA.z, accA[ri].z);
                accA[ri].w = fmaf(h, wA.w, accA[ri].w);
                accB[ri].x = fmaf(h, wB.x, accB[ri].x);
                accB[ri].y = fmaf(h, wB.y, accB[ri].y);
                accB[ri].z = fmaf(h, wB.z, accB[ri].z);
                accB[ri].w = fmaf(h, wB.w, accB[ri].w);
            }
        }
    }

    // ---- epilogue: relu(acc + b2), scatter-add by col ----
    #pragma unroll
    for (int ri = 0; ri < 8; ++ri) {
        const int e = e0 + ri;
        if (e < nedge) {
            const int col = scolL[e];
            float* o = out + (size_t)col * OC + c0;
            float4 va = accA[ri], vb = accB[ri];
            va.x = fmaxf(va.x + b2a.x, 0.f); va.y = fmaxf(va.y + b2a.y, 0.f);
            va.z = fmaxf(va.z + b2a.z, 0.f); va.w = fmaxf(va.w + b2a.w, 0.f);
            vb.x = fmaxf(vb.x + b2b.x, 0.f); vb.y = fmaxf(vb.y + b2b.y, 0.f);
            vb.z = fmaxf(vb.z + b2b.z, 0.f); vb.w = fmaxf(vb.w + b2b.w, 0.f);
            atomicAdd(o + 0, va.x); atomicAdd(o + 1, va.y);
            atomicAdd(o + 2, va.z); atomicAdd(o + 3, va.w);
            atomicAdd(o + 4, vb.x); atomicAdd(o + 5, vb.y);
            atomicAdd(o + 6, vb.z); atomicAdd(o + 7, vb.w);
        }
    }
}

#define LDS_BYTES ((4096 + 4096 + 512 + 512) * 16 + EPB * 2 * 4)

extern "C" void kernel_launch(void* const* d_in, const int* in_sizes, int n_in,
                              void* d_out, int out_size, void* d_ws, size_t ws_size,
                              hipStream_t stream) {
    const float* x    = (const float*)d_in[0];
    const int*   eidx = (const int*)d_in[1];
    const float* ea   = (const float*)d_in[2];
    const float* W1   = (const float*)d_in[3];
    const float* b1   = (const float*)d_in[4];
    const float* W2   = (const float*)d_in[5];
    const float* b2   = (const float*)d_in[6];
    float* out  = (float*)d_out;
    float* xw1b = (float*)d_ws;   // 4096*128*4 = 2 MB scratch

    const int E = in_sizes[1] / 2;

    hipMemsetAsync(d_out, 0, (size_t)out_size * sizeof(float), stream);
    k_xw1<<<NN / 8, 128, 0, stream>>>(x, W1, b1, xw1b);

    hipFuncSetAttribute(reinterpret_cast<const void*>(k_edge2),
                        hipFuncAttributeMaxDynamicSharedMemorySize, LDS_BYTES);
    const int nblocks = (E + EPB - 1) / EPB;
    k_edge2<<<nblocks, NT, LDS_BYTES, stream>>>(eidx, ea, xw1b, W1, W2, b2, out, E);
}

// Round 4
// 237.163 us; speedup vs baseline: 4.1284x; 4.1284x over previous
//
#include <hip/hip_runtime.h>
#include <hip/hip_bf16.h>

#define NN 4096
#define IC 128
#define OC 128
#define ED 16
#define EPB 128
#define NT 256
#define NSLOT 16

// raw barrier: drain LDS ops only; global loads/atomics stay in flight
#define BAR() do { asm volatile("s_waitcnt lgkmcnt(0)" ::: "memory"); \
    __builtin_amdgcn_s_barrier(); \
    __builtin_amdgcn_sched_barrier(0); } while (0)

// ---------------- Phase 1: xw1b[n][c] = b1[c] + sum_k x[n][k]*W1[k][c] ----
__global__ __launch_bounds__(128) void k_xw1(
    const float* __restrict__ x, const float* __restrict__ W1,
    const float* __restrict__ b1, float* __restrict__ xw1b)
{
    __shared__ float xs[8][IC];
    const int t = threadIdx.x;
    const int r0 = blockIdx.x * 8;
    #pragma unroll
    for (int r = 0; r < 8; ++r) xs[r][t] = x[(size_t)(r0 + r) * IC + t];
    __syncthreads();
    float acc[8];
    const float bb = b1[t];
    #pragma unroll
    for (int r = 0; r < 8; ++r) acc[r] = bb;
    #pragma unroll 4
    for (int k = 0; k < IC; ++k) {
        const float w = W1[(size_t)k * OC + t];
        #pragma unroll
        for (int r = 0; r < 8; ++r) acc[r] = fmaf(xs[r][k], w, acc[r]);
    }
    #pragma unroll
    for (int r = 0; r < 8; ++r) xw1b[(size_t)(r0 + r) * OC + t] = acc[r];
}

// ---------------- CSR build: hist -> scan -> scatter ----------------------
__global__ void k_hist(const int* __restrict__ eidx, int* __restrict__ hist, int E) {
    const int i = blockIdx.x * blockDim.x + threadIdx.x;
    if (i < E) atomicAdd(&hist[eidx[E + i]], 1);
}

__global__ __launch_bounds__(256) void k_scan(
    const int* __restrict__ hist, int* __restrict__ cursor)
{
    __shared__ int tot[256];
    __shared__ int base[256];
    const int t = threadIdx.x;
    int loc[16];
    int s = 0;
    #pragma unroll
    for (int j = 0; j < 16; ++j) { loc[j] = s; s += hist[t * 16 + j]; }
    tot[t] = s;
    __syncthreads();
    if (t == 0) {
        int a = 0;
        for (int i = 0; i < 256; ++i) { base[i] = a; a += tot[i]; }
    }
    __syncthreads();
    const int b = base[t];
    #pragma unroll
    for (int j = 0; j < 16; ++j) cursor[t * 16 + j] = b + loc[j];
}

__global__ void k_scatter(const int* __restrict__ eidx, int* __restrict__ cursor,
                          int2* __restrict__ csr, int E) {
    const int i = blockIdx.x * blockDim.x + threadIdx.x;
    if (i < E) {
        const int row = eidx[i];
        const int col = eidx[E + i];
        const int pos = atomicAdd(&cursor[col], 1);
        csr[pos] = make_int2(row, col);
    }
}

// ---------------- Phase 2: CSR-ordered edge batches -----------------------
// Persistent: 256 blocks (1/CU), each handles nper contiguous 128-edge
// batches. W2 (64KB) + W1e (8KB) staged in LDS once. Per batch:
//   gather ea -> eaL (swizzled), xw1b rows -> regs; layer1 -> h1s (swizzled);
//   layer2 register-tiled GEMM (8e x 8c/thread); epilogue: relu(.+b2),
//   register run-combine over sorted cols, ds_add into 16-slot lacc,
//   flush ~span*128 global atomics (vs 16384 before).
__global__ __launch_bounds__(NT, 1) void k_edge3(
    const int2* __restrict__ csr, const float* __restrict__ eattr,
    const float* __restrict__ xw1b, const float* __restrict__ W1,
    const float* __restrict__ W2, const float* __restrict__ b2,
    float* __restrict__ out, int E)
{
    extern __shared__ char smem[];
    float4* const W2L  = (float4*)smem;        // [128][32] f4 = 64KB
    float4* const h1s  = W2L + 4096;           // [128][32] f4 = 64KB (swz)
    float4* const eaL  = h1s + 4096;           // [128][4]  f4 =  8KB (swz)
    float4* const w1L  = eaL + 512;            // [16][32]  f4 =  8KB
    float*  const lacc = (float*)(w1L + 512);  // [16][128] f32 = 8KB
    int*    const srowL = (int*)(lacc + NSLOT * OC); // [128]
    int*    const scolL = srowL + EPB;               // [128]

    const int t  = threadIdx.x;
    const int cg = t & 15;
    const int eg = t >> 4;
    const int c0 = cg << 3;
    const int e0 = eg << 3;
    const int sz = eg & 3;

    // ---- stage weights once ----
    const float4* W2v = (const float4*)W2;
    #pragma unroll
    for (int i = 0; i < 16; ++i) W2L[t + NT * i] = W2v[t + NT * i];
    const float4* W1v = (const float4*)(W1 + (size_t)IC * OC);
    w1L[t]      = W1v[t];
    w1L[t + NT] = W1v[t + NT];
    const float4* b2v = (const float4*)b2;
    const float4 b2a = b2v[cg * 2], b2b = b2v[cg * 2 + 1];

    const int nb   = (E + EPB - 1) / EPB;
    const int nper = (nb + gridDim.x - 1) / gridDim.x;
    const int ib0  = blockIdx.x * nper;
    const int ib1  = min(nb, ib0 + nper);

    for (int ib = ib0; ib < ib1; ++ib) {
        const int ebase = ib * EPB;
        const int nedge = min(EPB, E - ebase);
        if (nedge <= 0) break;

        BAR();  // prev flush reads done; weights staged (first iter)

        // ---- zero lacc + load indices ----
        #pragma unroll
        for (int i = 0; i < NSLOT * OC / NT; ++i) lacc[t + NT * i] = 0.f;
        if (t < EPB && t < nedge) {
            const int2 rc = csr[ebase + t];
            srowL[t] = rc.x;
            scolL[t] = rc.y;
        }
        BAR();

        // ---- gather ea -> eaL, xw1b -> regs ----
        const int em = t >> 1, half = t & 1;
        float4 eA = make_float4(0.f, 0.f, 0.f, 0.f), eB = eA;
        if (em < nedge) {
            const float4* p = (const float4*)(eattr +
                ((size_t)srowL[em] * NN + scolL[em]) * ED);
            eA = p[half * 2]; eB = p[half * 2 + 1];
        }
        float4 xa[8], xb[8];
        #pragma unroll
        for (int ri = 0; ri < 8; ++ri) {
            const int e = e0 + ri;
            float4 za = make_float4(0.f, 0.f, 0.f, 0.f), zb = za;
            if (e < nedge) {
                const float4* p = (const float4*)(xw1b + (size_t)srowL[e] * OC + c0);
                za = p[0]; zb = p[1];
            }
            xa[ri] = za; xb[ri] = zb;
        }
        const int esz = (em >> 3) & 3;
        eaL[(em * 4 + half * 2)     ^ esz] = eA;
        eaL[(em * 4 + half * 2 + 1) ^ esz] = eB;
        BAR();

        // ---- layer 1 ----
        float4 ha[8], hb[8];
        #pragma unroll
        for (int ri = 0; ri < 8; ++ri) { ha[ri] = xa[ri]; hb[ri] = xb[ri]; }
        #pragma unroll
        for (int dc = 0; dc < 4; ++dc) {
            float4 ev[8];
            #pragma unroll
            for (int ri = 0; ri < 8; ++ri)
                ev[ri] = eaL[((e0 + ri) * 4 + dc) ^ sz];
            #pragma unroll
            for (int dd = 0; dd < 4; ++dd) {
                const int d = dc * 4 + dd;
                const float4 wA = w1L[d * 32 + cg * 2];
                const float4 wB = w1L[d * 32 + cg * 2 + 1];
                #pragma unroll
                for (int ri = 0; ri < 8; ++ri) {
                    const float evd = (dd == 0) ? ev[ri].x : (dd == 1) ? ev[ri].y
                                     : (dd == 2) ? ev[ri].z : ev[ri].w;
                    ha[ri].x = fmaf(evd, wA.x, ha[ri].x);
                    ha[ri].y = fmaf(evd, wA.y, ha[ri].y);
                    ha[ri].z = fmaf(evd, wA.z, ha[ri].z);
                    ha[ri].w = fmaf(evd, wA.w, ha[ri].w);
                    hb[ri].x = fmaf(evd, wB.x, hb[ri].x);
                    hb[ri].y = fmaf(evd, wB.y, hb[ri].y);
                    hb[ri].z = fmaf(evd, wB.z, hb[ri].z);
                    hb[ri].w = fmaf(evd, wB.w, hb[ri].w);
                }
            }
        }
        #pragma unroll
        for (int ri = 0; ri < 8; ++ri) {
            float4 va = ha[ri], vb = hb[ri];
            va.x = fmaxf(va.x, 0.f); va.y = fmaxf(va.y, 0.f);
            va.z = fmaxf(va.z, 0.f); va.w = fmaxf(va.w, 0.f);
            vb.x = fmaxf(vb.x, 0.f); vb.y = fmaxf(vb.y, 0.f);
            vb.z = fmaxf(vb.z, 0.f); vb.w = fmaxf(vb.w, 0.f);
            h1s[((e0 + ri) * 32 + cg * 2)     ^ sz] = va;
            h1s[((e0 + ri) * 32 + cg * 2 + 1) ^ sz] = vb;
        }
        BAR();

        // ---- layer 2: register-tiled GEMM ----
        float4 accA[8], accB[8];
        #pragma unroll
        for (int ri = 0; ri < 8; ++ri) {
            accA[ri] = make_float4(0.f, 0.f, 0.f, 0.f);
            accB[ri] = accA[ri];
        }
        for (int k4 = 0; k4 < 32; ++k4) {
            float4 hv[8];
            #pragma unroll
            for (int ri = 0; ri < 8; ++ri)
                hv[ri] = h1s[((e0 + ri) * 32 + k4) ^ sz];
            #pragma unroll
            for (int kk = 0; kk < 4; ++kk) {
                const float4 wA = W2L[(k4 * 4 + kk) * 32 + cg * 2];
                const float4 wB = W2L[(k4 * 4 + kk) * 32 + cg * 2 + 1];
                #pragma unroll
                for (int ri = 0; ri < 8; ++ri) {
                    const float h = (kk == 0) ? hv[ri].x : (kk == 1) ? hv[ri].y
                                   : (kk == 2) ? hv[ri].z : hv[ri].w;
                    accA[ri].x = fmaf(h, wA.x, accA[ri].x);
                    accA[ri].y = fmaf(h, wA.y, accA[ri].y);
                    accA[ri].z = fmaf(h, wA.z, accA[ri].z);
                    accA[ri].w = fmaf(h, wA.w, accA[ri].w);
                    accB[ri].x = fmaf(h, wB.x, accB[ri].x);
                    accB[ri].y = fmaf(h, wB.y, accB[ri].y);
                    accB[ri].z = fmaf(h, wB.z, accB[ri].z);
                    accB[ri].w = fmaf(h, wB.w, accB[ri].w);
                }
            }
        }

        // ---- epilogue: relu(acc+b2), run-combine sorted cols, ds_add ----
        const int colbase = scolL[0];
        if (e0 < nedge) {
            int   ccur = scolL[e0];
            float4 sa = make_float4(0.f, 0.f, 0.f, 0.f), sb = sa;
            bool first = true;
            #pragma unroll
            for (int ri = 0; ri < 8; ++ri) {
                const int e = e0 + ri;
                if (e >= nedge) break;
                float4 va = accA[ri], vb = accB[ri];
                va.x = fmaxf(va.x + b2a.x, 0.f); va.y = fmaxf(va.y + b2a.y, 0.f);
                va.z = fmaxf(va.z + b2a.z, 0.f); va.w = fmaxf(va.w + b2a.w, 0.f);
                vb.x = fmaxf(vb.x + b2b.x, 0.f); vb.y = fmaxf(vb.y + b2b.y, 0.f);
                vb.z = fmaxf(vb.z + b2b.z, 0.f); vb.w = fmaxf(vb.w + b2b.w, 0.f);
                const int c = scolL[e];
                if (!first && c == ccur) {
                    sa.x += va.x; sa.y += va.y; sa.z += va.z; sa.w += va.w;
                    sb.x += vb.x; sb.y += vb.y; sb.z += vb.z; sb.w += vb.w;
                } else {
                    if (!first) {
                        const int slot = ccur - colbase;
                        if (slot < NSLOT) {
                            float* L = lacc + slot * OC + c0;
                            if (sa.x != 0.f) atomicAdd(L + 0, sa.x);
                            if (sa.y != 0.f) atomicAdd(L + 1, sa.y);
                            if (sa.z != 0.f) atomicAdd(L + 2, sa.z);
                            if (sa.w != 0.f) atomicAdd(L + 3, sa.w);
                            if (sb.x != 0.f) atomicAdd(L + 4, sb.x);
                            if (sb.y != 0.f) atomicAdd(L + 5, sb.y);
                            if (sb.z != 0.f) atomicAdd(L + 6, sb.z);
                            if (sb.w != 0.f) atomicAdd(L + 7, sb.w);
                        } else {
                            float* O = out + (size_t)ccur * OC + c0;
                            if (sa.x != 0.f) atomicAdd(O + 0, sa.x);
                            if (sa.y != 0.f) atomicAdd(O + 1, sa.y);
                            if (sa.z != 0.f) atomicAdd(O + 2, sa.z);
                            if (sa.w != 0.f) atomicAdd(O + 3, sa.w);
                            if (sb.x != 0.f) atomicAdd(O + 4, sb.x);
                            if (sb.y != 0.f) atomicAdd(O + 5, sb.y);
                            if (sb.z != 0.f) atomicAdd(O + 6, sb.z);
                            if (sb.w != 0.f) atomicAdd(O + 7, sb.w);
                        }
                    }
                    ccur = c; sa = va; sb = vb; first = false;
                }
            }
            if (!first) {
                const int slot = ccur - colbase;
                if (slot < NSLOT) {
                    float* L = lacc + slot * OC + c0;
                    if (sa.x != 0.f) atomicAdd(L + 0, sa.x);
                    if (sa.y != 0.f) atomicAdd(L + 1, sa.y);
                    if (sa.z != 0.f) atomicAdd(L + 2, sa.z);
                    if (sa.w != 0.f) atomicAdd(L + 3, sa.w);
                    if (sb.x != 0.f) atomicAdd(L + 4, sb.x);
                    if (sb.y != 0.f) atomicAdd(L + 5, sb.y);
                    if (sb.z != 0.f) atomicAdd(L + 6, sb.z);
                    if (sb.w != 0.f) atomicAdd(L + 7, sb.w);
                } else {
                    float* O = out + (size_t)ccur * OC + c0;
                    if (sa.x != 0.f) atomicAdd(O + 0, sa.x);
                    if (sa.y != 0.f) atomicAdd(O + 1, sa.y);
                    if (sa.z != 0.f) atomicAdd(O + 2, sa.z);
                    if (sa.w != 0.f) atomicAdd(O + 3, sa.w);
                    if (sb.x != 0.f) atomicAdd(O + 4, sb.x);
                    if (sb.y != 0.f) atomicAdd(O + 5, sb.y);
                    if (sb.z != 0.f) atomicAdd(O + 6, sb.z);
                    if (sb.w != 0.f) atomicAdd(O + 7, sb.w);
                }
            }
        }
        BAR();  // lacc complete

        // ---- flush lacc -> out (fire-and-forget atomics) ----
        int span = scolL[nedge - 1] - colbase + 1;
        if (span > NSLOT) span = NSLOT;
        for (int idx = t; idx < span * OC; idx += NT) {
            const float v = lacc[idx];
            if (v != 0.f)
                atomicAdd(&out[(size_t)(colbase + (idx >> 7)) * OC + (idx & 127)], v);
        }
    }
}

#define LDS_BYTES ((4096 + 4096 + 512 + 512) * 16 + NSLOT * OC * 4 + EPB * 2 * 4)

extern "C" void kernel_launch(void* const* d_in, const int* in_sizes, int n_in,
                              void* d_out, int out_size, void* d_ws, size_t ws_size,
                              hipStream_t stream) {
    const float* x    = (const float*)d_in[0];
    const int*   eidx = (const int*)d_in[1];
    const float* ea   = (const float*)d_in[2];
    const float* W1   = (const float*)d_in[3];
    const float* b1   = (const float*)d_in[4];
    const float* W2   = (const float*)d_in[5];
    const float* b2   = (const float*)d_in[6];
    float* out = (float*)d_out;

    const int E = in_sizes[1] / 2;

    // workspace layout
    char* ws = (char*)d_ws;
    float* xw1b  = (float*)ws;                        // 2 MB
    int*   hist  = (int*)(ws + 2097152);              // 16 KB
    int*   cursor= (int*)(ws + 2097152 + 16384);      // 16 KB
    int2*  csr   = (int2*)(ws + 2097152 + 32768);     // 2 MB

    hipMemsetAsync(d_out, 0, (size_t)out_size * sizeof(float), stream);
    hipMemsetAsync(hist, 0, 4096 * sizeof(int), stream);

    k_xw1<<<NN / 8, 128, 0, stream>>>(x, W1, b1, xw1b);
    k_hist<<<(E + 255) / 256, 256, 0, stream>>>(eidx, hist, E);
    k_scan<<<1, 256, 0, stream>>>(hist, cursor);
    k_scatter<<<(E + 255) / 256, 256, 0, stream>>>(eidx, cursor, csr, E);

    hipFuncSetAttribute(reinterpret_cast<const void*>(k_edge3),
                        hipFuncAttributeMaxDynamicSharedMemorySize, LDS_BYTES);
    k_edge3<<<256, NT, LDS_BYTES, stream>>>(csr, ea, xw1b, W1, W2, b2, out, E);
}

// Round 5
// 167.275 us; speedup vs baseline: 5.8533x; 1.4178x over previous
//
#include <hip/hip_runtime.h>
#include <hip/hip_bf16.h>

#define NN 4096
#define IC 128
#define OC 128
#define ED 16
#define EPB 128
#define NT 256
#define NSLOT 8
#define NBLK 256

typedef __bf16 bf16x8 __attribute__((ext_vector_type(8)));
typedef float  f32x4  __attribute__((ext_vector_type(4)));

// raw barrier: drain LDS ops only; global loads/atomics stay in flight
#define BAR() do { asm volatile("s_waitcnt lgkmcnt(0)" ::: "memory"); \
    __builtin_amdgcn_s_barrier(); \
    __builtin_amdgcn_sched_barrier(0); } while (0)

__device__ __forceinline__ unsigned short bf16u(float f) {   // RNE f32->bf16
    unsigned int u = __float_as_uint(f);
    u = (u + 0x7FFFu + ((u >> 16) & 1u)) >> 16;
    return (unsigned short)u;
}
__device__ __forceinline__ float bf16tof(unsigned short h) {
    return __uint_as_float(((unsigned int)h) << 16);
}
__device__ __forceinline__ int swzk(int row) { return (row ^ (row >> 3)) & 7; }

// ---------------- Phase 1: xw1b[n][c] = b1[c] + sum_k x[n][k]*W1[k][c] ----
__global__ __launch_bounds__(128) void k_xw1(
    const float* __restrict__ x, const float* __restrict__ W1,
    const float* __restrict__ b1, float* __restrict__ xw1b)
{
    __shared__ float xs[8][IC];
    const int t = threadIdx.x;
    const int r0 = blockIdx.x * 8;
    #pragma unroll
    for (int r = 0; r < 8; ++r) xs[r][t] = x[(size_t)(r0 + r) * IC + t];
    __syncthreads();
    float acc[8];
    const float bb = b1[t];
    #pragma unroll
    for (int r = 0; r < 8; ++r) acc[r] = bb;
    #pragma unroll 4
    for (int k = 0; k < IC; ++k) {
        const float w = W1[(size_t)k * OC + t];
        #pragma unroll
        for (int r = 0; r < 8; ++r) acc[r] = fmaf(xs[r][k], w, acc[r]);
    }
    #pragma unroll
    for (int r = 0; r < 8; ++r) xw1b[(size_t)(r0 + r) * OC + t] = acc[r];
}

// ---------------- CSR build: hist -> scan -> scatter ----------------------
__global__ void k_hist(const int* __restrict__ eidx, int* __restrict__ hist, int E) {
    const int i = blockIdx.x * blockDim.x + threadIdx.x;
    if (i < E) atomicAdd(&hist[eidx[E + i]], 1);
}

__global__ __launch_bounds__(256) void k_scan(
    const int* __restrict__ hist, int* __restrict__ cursor)
{
    __shared__ int tot[256];
    __shared__ int base[256];
    const int t = threadIdx.x;
    int loc[16];
    int s = 0;
    #pragma unroll
    for (int j = 0; j < 16; ++j) { loc[j] = s; s += hist[t * 16 + j]; }
    tot[t] = s;
    __syncthreads();
    if (t == 0) {
        int a = 0;
        for (int i = 0; i < 256; ++i) { base[i] = a; a += tot[i]; }
    }
    __syncthreads();
    const int b = base[t];
    #pragma unroll
    for (int j = 0; j < 16; ++j) cursor[t * 16 + j] = b + loc[j];
}

__global__ void k_scatter(const int* __restrict__ eidx, int* __restrict__ cursor,
                          int2* __restrict__ csr, int E) {
    const int i = blockIdx.x * blockDim.x + threadIdx.x;
    if (i < E) {
        const int row = eidx[i];
        const int col = eidx[E + i];
        const int pos = atomicAdd(&cursor[col], 1);
        csr[pos] = make_int2(row, col);
    }
}

// ---------------- Phase 2: CSR batches, MFMA layer-2 ----------------------
// 256 persistent blocks (1/CU), 8 batches of 128 edges each.
// Layer 1 f32 VALU (as before). h1 and W2 stored as bf16 hi+lo planes in
// LDS (XOR-swizzled rows); layer 2 = 3-term split MFMA (hiA*hiB + loA*hiB +
// hiA*loB) on mfma_f32_16x16x32_bf16 -> ~f32 accuracy, f32 accumulate.
// edge_attr gathers register-prefetched one full batch ahead (hidden under
// compute); barriers are lgkmcnt-only so prefetch stays in flight.
__global__ __launch_bounds__(NT, 1) void k_edge4(
    const int2* __restrict__ csr, const float* __restrict__ eattr,
    const float* __restrict__ xw1b, const float* __restrict__ W1,
    const float* __restrict__ W2, const float* __restrict__ b2,
    float* __restrict__ out, int E)
{
    extern __shared__ char smem[];
    char*   const W2hi = smem;                        // 32KB bf16 [128n][128k] swz
    char*   const W2lo = smem + 32768;                // 32KB
    char*   const h1hi = smem + 65536;                // 32KB bf16 [128e][128k] swz
    char*   const h1lo = smem + 98304;                // 32KB
    float4* const eaL  = (float4*)(smem + 131072);    // [512] swz (8KB)
    float4* const w1L  = (float4*)(smem + 139264);    // [512] (8KB)
    float*  const lacc = (float*)(smem + 147456);     // [8][128] (4KB)
    int*    const srowL = (int*)(smem + 151552);      // [2][128]
    int*    const scolL = srowL + 256;                // [2][128]

    const int t   = threadIdx.x;
    const int l   = t & 63;
    const int wid = t >> 6;
    const int cg  = t & 15, eg = t >> 4;   // layer-1 tile: 8e x 8c per thread
    const int c0  = cg << 3, e0 = eg << 3;
    const int sz  = eg & 3;
    const int em  = t >> 1, half = t & 1;  // ea gather: 2 threads/edge
    const int esz = (em >> 3) & 3;

    // ---- stage weights once ----
    const float4* W1v = (const float4*)(W1 + (size_t)IC * OC);
    w1L[t]      = W1v[t];
    w1L[t + NT] = W1v[t + NT];
    {   // W2 -> transposed bf16 hi/lo planes: W2t[n][k]
        const int n = t >> 1, kh = (t & 1) * 64;
        const int key = swzk(n) << 4;
        for (int j0 = 0; j0 < 64; j0 += 8) {
            union { unsigned short us[8]; uint4 q; } Hh, Hl;
            #pragma unroll
            for (int j = 0; j < 8; ++j) {
                const float w = W2[(size_t)(kh + j0 + j) * OC + n];
                const unsigned short h = bf16u(w);
                Hh.us[j] = h;
                Hl.us[j] = bf16u(w - bf16tof(h));
            }
            const int a = n * 256 + (((kh + j0) * 2) ^ key);
            *(uint4*)(W2hi + a) = Hh.q;
            *(uint4*)(W2lo + a) = Hl.q;
        }
    }
    float b2r[8];
    #pragma unroll
    for (int nr = 0; nr < 8; ++nr) b2r[nr] = b2[nr * 16 + (l & 15)];

    const int nper = (E / EPB) / NBLK;          // 8 batches per block
    const int ibb  = blockIdx.x * nper;

    // idx for first batch -> buffer 0
    if (t < EPB) {
        const int2 rc = csr[(size_t)ibb * EPB + t];
        srowL[t] = rc.x;
        scolL[t] = rc.y;
    }
    __syncthreads();

    // prefetch ea for first batch
    float4 pA, pB;
    {
        const int r = srowL[em], c = scolL[em];
        const float4* p = (const float4*)(eattr + ((size_t)r * NN + c) * ED);
        pA = p[half * 2]; pB = p[half * 2 + 1];
    }

    int cur = 0;
    for (int ii = 0; ii < nper; ++ii) {
        const int ib  = ibb + ii;
        const int nxt = cur ^ 1;

        BAR();  // prev lacc flush done; srow[nxt] free for rewrite

        // 1. load idx(ib+1) (clamped on last iter)
        int2 idxn;
        {
            const int ibn = (ii + 1 < nper) ? (ib + 1) : ib;
            idxn = (t < EPB) ? csr[(size_t)ibn * EPB + t] : make_int2(0, 0);
        }
        // 2. zero lacc
        #pragma unroll
        for (int i = 0; i < 4; ++i) lacc[t + NT * i] = 0.f;
        // 3. write idx(ib+1) -> buffer nxt
        if (t < EPB) { srowL[nxt * 128 + t] = idxn.x; scolL[nxt * 128 + t] = idxn.y; }
        // 4. stage eaL <- prefetched regs (vmcnt wait lands here); issue xw loads
        eaL[(em * 4 + half * 2)     ^ esz] = pA;
        eaL[(em * 4 + half * 2 + 1) ^ esz] = pB;
        float4 xa[8], xb[8];
        #pragma unroll
        for (int ri = 0; ri < 8; ++ri) {
            const int row = srowL[cur * 128 + e0 + ri];
            const float4* p = (const float4*)(xw1b + (size_t)row * OC + c0);
            xa[ri] = p[0]; xb[ri] = p[1];
        }
        BAR();  // eaL + srow[nxt] visible

        // 6. layer 1 (f32)
        float4 ha[8], hb[8];
        #pragma unroll
        for (int ri = 0; ri < 8; ++ri) { ha[ri] = xa[ri]; hb[ri] = xb[ri]; }
        #pragma unroll
        for (int dc = 0; dc < 4; ++dc) {
            float4 ev[8];
            #pragma unroll
            for (int ri = 0; ri < 8; ++ri)
                ev[ri] = eaL[((e0 + ri) * 4 + dc) ^ sz];
            #pragma unroll
            for (int dd = 0; dd < 4; ++dd) {
                const int d = dc * 4 + dd;
                const float4 wA = w1L[d * 32 + cg * 2];
                const float4 wB = w1L[d * 32 + cg * 2 + 1];
                #pragma unroll
                for (int ri = 0; ri < 8; ++ri) {
                    const float evd = (dd == 0) ? ev[ri].x : (dd == 1) ? ev[ri].y
                                     : (dd == 2) ? ev[ri].z : ev[ri].w;
                    ha[ri].x = fmaf(evd, wA.x, ha[ri].x);
                    ha[ri].y = fmaf(evd, wA.y, ha[ri].y);
                    ha[ri].z = fmaf(evd, wA.z, ha[ri].z);
                    ha[ri].w = fmaf(evd, wA.w, ha[ri].w);
                    hb[ri].x = fmaf(evd, wB.x, hb[ri].x);
                    hb[ri].y = fmaf(evd, wB.y, hb[ri].y);
                    hb[ri].z = fmaf(evd, wB.z, hb[ri].z);
                    hb[ri].w = fmaf(evd, wB.w, hb[ri].w);
                }
            }
        }
        // relu + bf16 hi/lo split -> h1 planes
        #pragma unroll
        for (int ri = 0; ri < 8; ++ri) {
            const int row = e0 + ri;
            float v[8] = { ha[ri].x, ha[ri].y, ha[ri].z, ha[ri].w,
                           hb[ri].x, hb[ri].y, hb[ri].z, hb[ri].w };
            union { unsigned short us[8]; uint4 q; } Hh, Hl;
            #pragma unroll
            for (int j = 0; j < 8; ++j) {
                const float f = fmaxf(v[j], 0.f);
                const unsigned short h = bf16u(f);
                Hh.us[j] = h;
                Hl.us[j] = bf16u(f - bf16tof(h));
            }
            const int boff = (cg * 16) ^ (swzk(row) << 4);
            *(uint4*)(h1hi + row * 256 + boff) = Hh.q;
            *(uint4*)(h1lo + row * 256 + boff) = Hl.q;
        }
        // 7. issue ea prefetch for next batch (indices in buffer nxt)
        {
            const int r = srowL[nxt * 128 + em], c = scolL[nxt * 128 + em];
            const float4* p = (const float4*)(eattr + ((size_t)r * NN + c) * ED);
            pA = p[half * 2]; pB = p[half * 2 + 1];
        }
        BAR();  // h1 planes visible

        // 9. layer 2: 3-term split MFMA. Wave tile 32e x 128c.
        f32x4 acc[2][8];
        #pragma unroll
        for (int mr = 0; mr < 2; ++mr)
            #pragma unroll
            for (int nr = 0; nr < 8; ++nr)
                acc[mr][nr] = (f32x4){0.f, 0.f, 0.f, 0.f};
        const int arow0 = wid * 32 + (l & 15);
        const int arow1 = arow0 + 16;
        const int akey0 = swzk(arow0) << 4, akey1 = swzk(arow1) << 4;
        #pragma unroll
        for (int kc = 0; kc < 4; ++kc) {
            const int kb = kc * 64 + ((l >> 4) << 4);
            const bf16x8 aH0 = *(const bf16x8*)(h1hi + arow0 * 256 + (kb ^ akey0));
            const bf16x8 aH1 = *(const bf16x8*)(h1hi + arow1 * 256 + (kb ^ akey1));
            const bf16x8 aL0 = *(const bf16x8*)(h1lo + arow0 * 256 + (kb ^ akey0));
            const bf16x8 aL1 = *(const bf16x8*)(h1lo + arow1 * 256 + (kb ^ akey1));
            #pragma unroll
            for (int nr = 0; nr < 8; ++nr) {
                const int brow = nr * 16 + (l & 15);
                const int ba = brow * 256 + (kb ^ (swzk(brow) << 4));
                const bf16x8 bH = *(const bf16x8*)(W2hi + ba);
                const bf16x8 bL = *(const bf16x8*)(W2lo + ba);
                acc[0][nr] = __builtin_amdgcn_mfma_f32_16x16x32_bf16(aH0, bH, acc[0][nr], 0, 0, 0);
                acc[1][nr] = __builtin_amdgcn_mfma_f32_16x16x32_bf16(aH1, bH, acc[1][nr], 0, 0, 0);
                acc[0][nr] = __builtin_amdgcn_mfma_f32_16x16x32_bf16(aL0, bH, acc[0][nr], 0, 0, 0);
                acc[1][nr] = __builtin_amdgcn_mfma_f32_16x16x32_bf16(aL1, bH, acc[1][nr], 0, 0, 0);
                acc[0][nr] = __builtin_amdgcn_mfma_f32_16x16x32_bf16(aH0, bL, acc[0][nr], 0, 0, 0);
                acc[1][nr] = __builtin_amdgcn_mfma_f32_16x16x32_bf16(aH1, bL, acc[1][nr], 0, 0, 0);
            }
        }

        // 10. epilogue: D row = edge (lane>>4)*4+r, col = nr*16+(lane&15).
        //     relu(acc+b2), run-combine 4 consecutive sorted edges, lacc/global.
        const int colbase = scolL[cur * 128];
        #pragma unroll
        for (int mr = 0; mr < 2; ++mr) {
            const int eb = wid * 32 + mr * 16 + ((l >> 4) << 2);
            float s[8];
            int ccur = scolL[cur * 128 + eb];
            #pragma unroll
            for (int nr = 0; nr < 8; ++nr)
                s[nr] = fmaxf(acc[mr][nr][0] + b2r[nr], 0.f);
            #pragma unroll
            for (int r = 1; r < 4; ++r) {
                const int c = scolL[cur * 128 + eb + r];
                if (c != ccur) {
                    const int slot = ccur - colbase;
                    if (slot < NSLOT) {
                        #pragma unroll
                        for (int nr = 0; nr < 8; ++nr)
                            if (s[nr] != 0.f)
                                atomicAdd(&lacc[slot * OC + nr * 16 + (l & 15)], s[nr]);
                    } else {
                        #pragma unroll
                        for (int nr = 0; nr < 8; ++nr)
                            if (s[nr] != 0.f)
                                atomicAdd(&out[(size_t)ccur * OC + nr * 16 + (l & 15)], s[nr]);
                    }
                    ccur = c;
                    #pragma unroll
                    for (int nr = 0; nr < 8; ++nr)
                        s[nr] = fmaxf(acc[mr][nr][r] + b2r[nr], 0.f);
                } else {
                    #pragma unroll
                    for (int nr = 0; nr < 8; ++nr)
                        s[nr] += fmaxf(acc[mr][nr][r] + b2r[nr], 0.f);
                }
            }
            {
                const int slot = ccur - colbase;
                if (slot < NSLOT) {
                    #pragma unroll
                    for (int nr = 0; nr < 8; ++nr)
                        if (s[nr] != 0.f)
                            atomicAdd(&lacc[slot * OC + nr * 16 + (l & 15)], s[nr]);
                } else {
                    #pragma unroll
                    for (int nr = 0; nr < 8; ++nr)
                        if (s[nr] != 0.f)
                            atomicAdd(&out[(size_t)ccur * OC + nr * 16 + (l & 15)], s[nr]);
                }
            }
        }
        BAR();  // lacc complete

        // 11. flush lacc -> out (fire-and-forget atomics)
        int span = scolL[cur * 128 + 127] - colbase + 1;
        if (span > NSLOT) span = NSLOT;
        for (int idx = t; idx < span * OC; idx += NT) {
            const float v = lacc[idx];
            if (v != 0.f)
                atomicAdd(&out[(size_t)(colbase + (idx >> 7)) * OC + (idx & 127)], v);
        }
        cur = nxt;
    }
}

#define LDS_BYTES 153600

extern "C" void kernel_launch(void* const* d_in, const int* in_sizes, int n_in,
                              void* d_out, int out_size, void* d_ws, size_t ws_size,
                              hipStream_t stream) {
    const float* x    = (const float*)d_in[0];
    const int*   eidx = (const int*)d_in[1];
    const float* ea   = (const float*)d_in[2];
    const float* W1   = (const float*)d_in[3];
    const float* b1   = (const float*)d_in[4];
    const float* W2   = (const float*)d_in[5];
    const float* b2   = (const float*)d_in[6];
    float* out = (float*)d_out;

    const int E = in_sizes[1] / 2;

    char* ws = (char*)d_ws;
    float* xw1b   = (float*)ws;                        // 2 MB
    int*   hist   = (int*)(ws + 2097152);              // 16 KB
    int*   cursor = (int*)(ws + 2097152 + 16384);      // 16 KB
    int2*  csr    = (int2*)(ws + 2097152 + 32768);     // 2 MB

    hipMemsetAsync(d_out, 0, (size_t)out_size * sizeof(float), stream);
    hipMemsetAsync(hist, 0, 4096 * sizeof(int), stream);

    k_xw1<<<NN / 8, 128, 0, stream>>>(x, W1, b1, xw1b);
    k_hist<<<(E + 255) / 256, 256, 0, stream>>>(eidx, hist, E);
    k_scan<<<1, 256, 0, stream>>>(hist, cursor);
    k_scatter<<<(E + 255) / 256, 256, 0, stream>>>(eidx, cursor, csr, E);

    hipFuncSetAttribute(reinterpret_cast<const void*>(k_edge4),
                        hipFuncAttributeMaxDynamicSharedMemorySize, LDS_BYTES);
    k_edge4<<<NBLK, NT, LDS_BYTES, stream>>>(csr, ea, xw1b, W1, W2, b2, out, E);
}

// Round 6
// 155.529 us; speedup vs baseline: 6.2954x; 1.0755x over previous
//
#include <hip/hip_runtime.h>
#include <hip/hip_bf16.h>

#define NN 4096
#define IC 128
#define OC 128
#define ED 16
#define EPB 128
#define NT 512
#define NSLOT 8
#define NBLK 256

typedef __bf16 bf16x8 __attribute__((ext_vector_type(8)));
typedef float  f32x4  __attribute__((ext_vector_type(4)));

// raw barrier: drain LDS ops only; global loads/atomics stay in flight
#define BAR() do { asm volatile("s_waitcnt lgkmcnt(0)" ::: "memory"); \
    __builtin_amdgcn_s_barrier(); \
    __builtin_amdgcn_sched_barrier(0); } while (0)

__device__ __forceinline__ unsigned short bf16u(float f) {   // RNE f32->bf16
    unsigned int u = __float_as_uint(f);
    u = (u + 0x7FFFu + ((u >> 16) & 1u)) >> 16;
    return (unsigned short)u;
}
__device__ __forceinline__ float bf16tof(unsigned short h) {
    return __uint_as_float(((unsigned int)h) << 16);
}
__device__ __forceinline__ int swzk(int row) { return (row ^ (row >> 3)) & 7; }

// ---------------- Phase 1: xw1b[n][c] = b1[c] + sum_k x[n][k]*W1[k][c] ----
__global__ __launch_bounds__(128) void k_xw1(
    const float* __restrict__ x, const float* __restrict__ W1,
    const float* __restrict__ b1, float* __restrict__ xw1b)
{
    __shared__ float xs[8][IC];
    const int t = threadIdx.x;
    const int r0 = blockIdx.x * 8;
    #pragma unroll
    for (int r = 0; r < 8; ++r) xs[r][t] = x[(size_t)(r0 + r) * IC + t];
    __syncthreads();
    float acc[8];
    const float bb = b1[t];
    #pragma unroll
    for (int r = 0; r < 8; ++r) acc[r] = bb;
    #pragma unroll 4
    for (int k = 0; k < IC; ++k) {
        const float w = W1[(size_t)k * OC + t];
        #pragma unroll
        for (int r = 0; r < 8; ++r) acc[r] = fmaf(xs[r][k], w, acc[r]);
    }
    #pragma unroll
    for (int r = 0; r < 8; ++r) xw1b[(size_t)(r0 + r) * OC + t] = acc[r];
}

// ---------------- CSR build: hist -> scan -> scatter ----------------------
__global__ void k_hist(const int* __restrict__ eidx, int* __restrict__ hist, int E) {
    const int i = blockIdx.x * blockDim.x + threadIdx.x;
    if (i < E) atomicAdd(&hist[eidx[E + i]], 1);
}

__global__ __launch_bounds__(256) void k_scan(
    const int* __restrict__ hist, int* __restrict__ cursor)
{
    __shared__ int tot[256];
    __shared__ int base[256];
    const int t = threadIdx.x;
    int loc[16];
    int s = 0;
    #pragma unroll
    for (int j = 0; j < 16; ++j) { loc[j] = s; s += hist[t * 16 + j]; }
    tot[t] = s;
    __syncthreads();
    if (t == 0) {
        int a = 0;
        for (int i = 0; i < 256; ++i) { base[i] = a; a += tot[i]; }
    }
    __syncthreads();
    const int b = base[t];
    #pragma unroll
    for (int j = 0; j < 16; ++j) cursor[t * 16 + j] = b + loc[j];
}

__global__ void k_scatter(const int* __restrict__ eidx, int* __restrict__ cursor,
                          int2* __restrict__ csr, int E) {
    const int i = blockIdx.x * blockDim.x + threadIdx.x;
    if (i < E) {
        const int row = eidx[i];
        const int col = eidx[E + i];
        const int pos = atomicAdd(&cursor[col], 1);
        csr[pos] = make_int2(row, col);
    }
}

// ---------------- Phase 2: CSR batches, MFMA layer-2, 8 waves -------------
// 256 persistent blocks (1/CU), NT=512 -> 8 waves = 2 waves/SIMD for latency
// hiding (was 1). Same 128-edge batches, same 150KB LDS, same numerics.
// Layer 1: 4e x 8c per thread (f32). Layer 2: 1 m-tile (16 edges) per wave,
// 3-term bf16 hi/lo split MFMA, f32 accumulate.
__global__ __launch_bounds__(NT, 2) void k_edge5(
    const int2* __restrict__ csr, const float* __restrict__ eattr,
    const float* __restrict__ xw1b, const float* __restrict__ W1,
    const float* __restrict__ W2, const float* __restrict__ b2,
    float* __restrict__ out, int E)
{
    extern __shared__ char smem[];
    char*   const W2hi = smem;                        // 32KB bf16 [128n][128k] swz
    char*   const W2lo = smem + 32768;                // 32KB
    char*   const h1hi = smem + 65536;                // 32KB bf16 [128e][128k] swz
    char*   const h1lo = smem + 98304;                // 32KB
    float4* const eaL  = (float4*)(smem + 131072);    // [512] swz (8KB)
    float4* const w1L  = (float4*)(smem + 139264);    // [512] (8KB)
    float*  const lacc = (float*)(smem + 147456);     // [8][128] (4KB)
    int*    const srowL = (int*)(smem + 151552);      // [2][128]
    int*    const scolL = srowL + 256;                // [2][128]

    const int t   = threadIdx.x;
    const int l   = t & 63;
    const int wid = t >> 6;                 // 8 waves
    const int cg  = t & 15, eg = t >> 4;    // layer-1 tile: 4e x 8c; eg 0..31
    const int c0  = cg << 3, e0 = eg << 2;
    const int sz  = (eg >> 1) & 3;          // per-edge swizzle key: ((e>>3)&3)
    const int em  = t >> 2, q = t & 3;      // ea gather: 4 threads/edge
    const int esz = (em >> 3) & 3;

    // ---- stage weights once ----
    w1L[t] = ((const float4*)(W1 + (size_t)IC * OC))[t];
    {   // W2 -> transposed bf16 hi/lo planes: W2t[n][k]
        const int n = t >> 2, kh = (t & 3) * 32;
        const int key = swzk(n) << 4;
        for (int j0 = 0; j0 < 32; j0 += 8) {
            union { unsigned short us[8]; uint4 qv; } Hh, Hl;
            #pragma unroll
            for (int j = 0; j < 8; ++j) {
                const float w = W2[(size_t)(kh + j0 + j) * OC + n];
                const unsigned short h = bf16u(w);
                Hh.us[j] = h;
                Hl.us[j] = bf16u(w - bf16tof(h));
            }
            const int a = n * 256 + (((kh + j0) * 2) ^ key);
            *(uint4*)(W2hi + a) = Hh.qv;
            *(uint4*)(W2lo + a) = Hl.qv;
        }
    }
    float b2r[8];
    #pragma unroll
    for (int nr = 0; nr < 8; ++nr) b2r[nr] = b2[nr * 16 + (l & 15)];

    const int nper = (E / EPB) / NBLK;          // 8 batches per block
    const int ibb  = blockIdx.x * nper;

    // idx for first batch -> buffer 0
    if (t < EPB) {
        const int2 rc = csr[(size_t)ibb * EPB + t];
        srowL[t] = rc.x;
        scolL[t] = rc.y;
    }
    __syncthreads();

    // prefetch ea for first batch (1 float4 per thread)
    float4 pA;
    {
        const int r = srowL[em], c = scolL[em];
        pA = ((const float4*)(eattr + ((size_t)r * NN + c) * ED))[q];
    }

    int cur = 0;
    for (int ii = 0; ii < nper; ++ii) {
        const int ib  = ibb + ii;
        const int nxt = cur ^ 1;

        BAR();  // prev lacc flush done; srow[nxt] free for rewrite

        // 1. load idx(ib+1) (clamped on last iter)
        int2 idxn;
        {
            const int ibn = (ii + 1 < nper) ? (ib + 1) : ib;
            idxn = (t < EPB) ? csr[(size_t)ibn * EPB + t] : make_int2(0, 0);
        }
        // 2. zero lacc
        lacc[t] = 0.f; lacc[t + NT] = 0.f;
        // 3. write idx(ib+1) -> buffer nxt
        if (t < EPB) { srowL[nxt * 128 + t] = idxn.x; scolL[nxt * 128 + t] = idxn.y; }
        // 4. stage eaL <- prefetched reg; issue xw loads
        eaL[(em * 4 + q) ^ esz] = pA;
        float4 xa[4], xb[4];
        #pragma unroll
        for (int ri = 0; ri < 4; ++ri) {
            const int row = srowL[cur * 128 + e0 + ri];
            const float4* p = (const float4*)(xw1b + (size_t)row * OC + c0);
            xa[ri] = p[0]; xb[ri] = p[1];
        }
        BAR();  // eaL + srow[nxt] visible

        // 6. layer 1 (f32): 4e x 8c per thread
        float4 ha[4], hb[4];
        #pragma unroll
        for (int ri = 0; ri < 4; ++ri) { ha[ri] = xa[ri]; hb[ri] = xb[ri]; }
        #pragma unroll
        for (int dc = 0; dc < 4; ++dc) {
            float4 ev[4];
            #pragma unroll
            for (int ri = 0; ri < 4; ++ri)
                ev[ri] = eaL[((e0 + ri) * 4 + dc) ^ sz];
            #pragma unroll
            for (int dd = 0; dd < 4; ++dd) {
                const int d = dc * 4 + dd;
                const float4 wA = w1L[d * 32 + cg * 2];
                const float4 wB = w1L[d * 32 + cg * 2 + 1];
                #pragma unroll
                for (int ri = 0; ri < 4; ++ri) {
                    const float evd = (dd == 0) ? ev[ri].x : (dd == 1) ? ev[ri].y
                                     : (dd == 2) ? ev[ri].z : ev[ri].w;
                    ha[ri].x = fmaf(evd, wA.x, ha[ri].x);
                    ha[ri].y = fmaf(evd, wA.y, ha[ri].y);
                    ha[ri].z = fmaf(evd, wA.z, ha[ri].z);
                    ha[ri].w = fmaf(evd, wA.w, ha[ri].w);
                    hb[ri].x = fmaf(evd, wB.x, hb[ri].x);
                    hb[ri].y = fmaf(evd, wB.y, hb[ri].y);
                    hb[ri].z = fmaf(evd, wB.z, hb[ri].z);
                    hb[ri].w = fmaf(evd, wB.w, hb[ri].w);
                }
            }
        }
        // relu + bf16 hi/lo split -> h1 planes
        #pragma unroll
        for (int ri = 0; ri < 4; ++ri) {
            const int row = e0 + ri;
            float v[8] = { ha[ri].x, ha[ri].y, ha[ri].z, ha[ri].w,
                           hb[ri].x, hb[ri].y, hb[ri].z, hb[ri].w };
            union { unsigned short us[8]; uint4 qv; } Hh, Hl;
            #pragma unroll
            for (int j = 0; j < 8; ++j) {
                const float f = fmaxf(v[j], 0.f);
                const unsigned short h = bf16u(f);
                Hh.us[j] = h;
                Hl.us[j] = bf16u(f - bf16tof(h));
            }
            const int boff = (cg * 16) ^ (swzk(row) << 4);
            *(uint4*)(h1hi + row * 256 + boff) = Hh.qv;
            *(uint4*)(h1lo + row * 256 + boff) = Hl.qv;
        }
        // 7. issue ea prefetch for next batch (indices in buffer nxt)
        {
            const int r = srowL[nxt * 128 + em], c = scolL[nxt * 128 + em];
            pA = ((const float4*)(eattr + ((size_t)r * NN + c) * ED))[q];
        }
        BAR();  // h1 planes visible

        // 9. layer 2: 3-term split MFMA. Wave tile 16e x 128c.
        f32x4 acc[8];
        #pragma unroll
        for (int nr = 0; nr < 8; ++nr) acc[nr] = (f32x4){0.f, 0.f, 0.f, 0.f};
        const int arow = wid * 16 + (l & 15);
        const int akey = swzk(arow) << 4;
        #pragma unroll
        for (int kc = 0; kc < 4; ++kc) {
            const int kb = kc * 64 + ((l >> 4) << 4);      // byte offset in row
            const bf16x8 aH = *(const bf16x8*)(h1hi + arow * 256 + (kb ^ akey));
            const bf16x8 aL = *(const bf16x8*)(h1lo + arow * 256 + (kb ^ akey));
            #pragma unroll
            for (int nr = 0; nr < 8; ++nr) {
                const int brow = nr * 16 + (l & 15);
                const int ba = brow * 256 + (kb ^ (swzk(brow) << 4));
                const bf16x8 bH = *(const bf16x8*)(W2hi + ba);
                const bf16x8 bL = *(const bf16x8*)(W2lo + ba);
                acc[nr] = __builtin_amdgcn_mfma_f32_16x16x32_bf16(aH, bH, acc[nr], 0, 0, 0);
                acc[nr] = __builtin_amdgcn_mfma_f32_16x16x32_bf16(aL, bH, acc[nr], 0, 0, 0);
                acc[nr] = __builtin_amdgcn_mfma_f32_16x16x32_bf16(aH, bL, acc[nr], 0, 0, 0);
            }
        }

        // 10. epilogue: D row = edge (lane>>4)*4+r, col = nr*16+(lane&15).
        //     relu(acc+b2), run-combine 4 consecutive sorted edges, lacc/global.
        const int colbase = scolL[cur * 128];
        {
            const int eb = wid * 16 + ((l >> 4) << 2);
            float s[8];
            int ccur = scolL[cur * 128 + eb];
            #pragma unroll
            for (int nr = 0; nr < 8; ++nr)
                s[nr] = fmaxf(acc[nr][0] + b2r[nr], 0.f);
            #pragma unroll
            for (int r = 1; r < 4; ++r) {
                const int c = scolL[cur * 128 + eb + r];
                if (c != ccur) {
                    const int slot = ccur - colbase;
                    if (slot < NSLOT) {
                        #pragma unroll
                        for (int nr = 0; nr < 8; ++nr)
                            if (s[nr] != 0.f)
                                atomicAdd(&lacc[slot * OC + nr * 16 + (l & 15)], s[nr]);
                    } else {
                        #pragma unroll
                        for (int nr = 0; nr < 8; ++nr)
                            if (s[nr] != 0.f)
                                atomicAdd(&out[(size_t)ccur * OC + nr * 16 + (l & 15)], s[nr]);
                    }
                    ccur = c;
                    #pragma unroll
                    for (int nr = 0; nr < 8; ++nr)
                        s[nr] = fmaxf(acc[nr][r] + b2r[nr], 0.f);
                } else {
                    #pragma unroll
                    for (int nr = 0; nr < 8; ++nr)
                        s[nr] += fmaxf(acc[nr][r] + b2r[nr], 0.f);
                }
            }
            {
                const int slot = ccur - colbase;
                if (slot < NSLOT) {
                    #pragma unroll
                    for (int nr = 0; nr < 8; ++nr)
                        if (s[nr] != 0.f)
                            atomicAdd(&lacc[slot * OC + nr * 16 + (l & 15)], s[nr]);
                } else {
                    #pragma unroll
                    for (int nr = 0; nr < 8; ++nr)
                        if (s[nr] != 0.f)
                            atomicAdd(&out[(size_t)ccur * OC + nr * 16 + (l & 15)], s[nr]);
                }
            }
        }
        BAR();  // lacc complete

        // 11. flush lacc -> out (fire-and-forget atomics)
        int span = scolL[cur * 128 + 127] - colbase + 1;
        if (span > NSLOT) span = NSLOT;
        for (int idx = t; idx < span * OC; idx += NT) {
            const float v = lacc[idx];
            if (v != 0.f)
                atomicAdd(&out[(size_t)(colbase + (idx >> 7)) * OC + (idx & 127)], v);
        }
        cur = nxt;
    }
}

#define LDS_BYTES 153600

extern "C" void kernel_launch(void* const* d_in, const int* in_sizes, int n_in,
                              void* d_out, int out_size, void* d_ws, size_t ws_size,
                              hipStream_t stream) {
    const float* x    = (const float*)d_in[0];
    const int*   eidx = (const int*)d_in[1];
    const float* ea   = (const float*)d_in[2];
    const float* W1   = (const float*)d_in[3];
    const float* b1   = (const float*)d_in[4];
    const float* W2   = (const float*)d_in[5];
    const float* b2   = (const float*)d_in[6];
    float* out = (float*)d_out;

    const int E = in_sizes[1] / 2;

    char* ws = (char*)d_ws;
    float* xw1b   = (float*)ws;                        // 2 MB
    int*   hist   = (int*)(ws + 2097152);              // 16 KB
    int*   cursor = (int*)(ws + 2097152 + 16384);      // 16 KB
    int2*  csr    = (int2*)(ws + 2097152 + 32768);     // 2 MB

    hipMemsetAsync(d_out, 0, (size_t)out_size * sizeof(float), stream);
    hipMemsetAsync(hist, 0, 4096 * sizeof(int), stream);

    k_xw1<<<NN / 8, 128, 0, stream>>>(x, W1, b1, xw1b);
    k_hist<<<(E + 255) / 256, 256, 0, stream>>>(eidx, hist, E);
    k_scan<<<1, 256, 0, stream>>>(hist, cursor);
    k_scatter<<<(E + 255) / 256, 256, 0, stream>>>(eidx, cursor, csr, E);

    hipFuncSetAttribute(reinterpret_cast<const void*>(k_edge5),
                        hipFuncAttributeMaxDynamicSharedMemorySize, LDS_BYTES);
    k_edge5<<<NBLK, NT, LDS_BYTES, stream>>>(csr, ea, xw1b, W1, W2, b2, out, E);
}

// Round 7
// 151.590 us; speedup vs baseline: 6.4589x; 1.0260x over previous
//
#include <hip/hip_runtime.h>
#include <hip/hip_bf16.h>

#define NN 4096
#define IC 128
#define OC 128
#define ED 16
#define EPB 128
#define NT 512
#define NSLOT 8
#define NBLK 256

typedef __bf16 bf16x8 __attribute__((ext_vector_type(8)));
typedef float  f32x4  __attribute__((ext_vector_type(4)));

// raw barrier: drain LDS ops only; global loads/atomics stay in flight
#define BAR() do { asm volatile("s_waitcnt lgkmcnt(0)" ::: "memory"); \
    __builtin_amdgcn_s_barrier(); \
    __builtin_amdgcn_sched_barrier(0); } while (0)

__device__ __forceinline__ unsigned short bf16u(float f) {   // RNE f32->bf16
    unsigned int u = __float_as_uint(f);
    u = (u + 0x7FFFu + ((u >> 16) & 1u)) >> 16;
    return (unsigned short)u;
}
__device__ __forceinline__ float bf16tof(unsigned short h) {
    return __uint_as_float(((unsigned int)h) << 16);
}
__device__ __forceinline__ int swzk(int row) { return (row ^ (row >> 3)) & 7; }

// ---- Phase 1: xw1b = x@W1[:128] + b1; also zeroes out + hist (fused) ----
__global__ __launch_bounds__(128) void k_xw1(
    const float* __restrict__ x, const float* __restrict__ W1,
    const float* __restrict__ b1, float* __restrict__ xw1b,
    float* __restrict__ out, int* __restrict__ hist)
{
    __shared__ float xs[8][IC];
    const int t = threadIdx.x;
    const int r0 = blockIdx.x * 8;
    #pragma unroll
    for (int r = 0; r < 8; ++r) xs[r][t] = x[(size_t)(r0 + r) * IC + t];

    // fused zeroing: 512 blocks x 128 threads cover out (131072 float4)
    const float4 z = make_float4(0.f, 0.f, 0.f, 0.f);
    float4* o4 = (float4*)out;
    o4[blockIdx.x * 256 + t]       = z;
    o4[blockIdx.x * 256 + 128 + t] = z;
    if (blockIdx.x == 0) {
        int4* h4 = (int4*)hist;                 // 4096 ints = 1024 int4
        #pragma unroll
        for (int j = 0; j < 8; ++j) h4[j * 128 + t] = make_int4(0, 0, 0, 0);
    }

    __syncthreads();
    float acc[8];
    const float bb = b1[t];
    #pragma unroll
    for (int r = 0; r < 8; ++r) acc[r] = bb;
    #pragma unroll 4
    for (int k = 0; k < IC; ++k) {
        const float w = W1[(size_t)k * OC + t];
        #pragma unroll
        for (int r = 0; r < 8; ++r) acc[r] = fmaf(xs[r][k], w, acc[r]);
    }
    #pragma unroll
    for (int r = 0; r < 8; ++r) xw1b[(size_t)(r0 + r) * OC + t] = acc[r];
}

// ---------------- CSR build: hist -> scan -> scatter ----------------------
__global__ void k_hist(const int* __restrict__ eidx, int* __restrict__ hist, int E) {
    const int i = blockIdx.x * blockDim.x + threadIdx.x;
    if (i < E) atomicAdd(&hist[eidx[E + i]], 1);
}

__global__ __launch_bounds__(256) void k_scan(
    const int* __restrict__ hist, int* __restrict__ cursor)
{
    __shared__ int tot[256];
    __shared__ int base[256];
    const int t = threadIdx.x;
    int loc[16];
    int s = 0;
    #pragma unroll
    for (int j = 0; j < 16; ++j) { loc[j] = s; s += hist[t * 16 + j]; }
    tot[t] = s;
    __syncthreads();
    if (t == 0) {
        int a = 0;
        for (int i = 0; i < 256; ++i) { base[i] = a; a += tot[i]; }
    }
    __syncthreads();
    const int b = base[t];
    #pragma unroll
    for (int j = 0; j < 16; ++j) cursor[t * 16 + j] = b + loc[j];
}

__global__ void k_scatter(const int* __restrict__ eidx, int* __restrict__ cursor,
                          int2* __restrict__ csr, int E) {
    const int i = blockIdx.x * blockDim.x + threadIdx.x;
    if (i < E) {
        const int row = eidx[i];
        const int col = eidx[E + i];
        const int pos = atomicAdd(&cursor[col], 1);
        csr[pos] = make_int2(row, col);
    }
}

// ---------------- Phase 2: CSR batches, MFMA layer-2, deep prefetch -------
// 256 persistent blocks (1/CU), 8 waves (2/SIMD). Per 128-edge batch, ALL
// global reads (csr idx, xw1b rows, edge_attr) are register-prefetched one
// full batch ahead and consumed from registers -> the ~2000cy layer-2 +
// epilogue phase hides all L2/HBM latency; batch critical path has no
// global round-trips. Barriers drain lgkmcnt only.
__global__ __launch_bounds__(NT, 2) void k_edge6(
    const int2* __restrict__ csr, const float* __restrict__ eattr,
    const float* __restrict__ xw1b, const float* __restrict__ W1,
    const float* __restrict__ W2, const float* __restrict__ b2,
    float* __restrict__ out, int E)
{
    extern __shared__ char smem[];
    char*   const W2hi = smem;                        // 32KB bf16 [128n][128k] swz
    char*   const W2lo = smem + 32768;                // 32KB
    char*   const h1hi = smem + 65536;                // 32KB bf16 [128e][128k] swz
    char*   const h1lo = smem + 98304;                // 32KB
    float4* const eaL  = (float4*)(smem + 131072);    // [512] swz (8KB)
    float4* const w1L  = (float4*)(smem + 139264);    // [512] (8KB)
    float*  const lacc = (float*)(smem + 147456);     // [8][128] (4KB)
    int*    const srowL = (int*)(smem + 151552);      // [2][128]
    int*    const scolL = srowL + 256;                // [2][128]

    const int t   = threadIdx.x;
    const int l   = t & 63;
    const int wid = t >> 6;                 // 8 waves
    const int cg  = t & 15, eg = t >> 4;    // layer-1 tile: 4e x 8c; eg 0..31
    const int c0  = cg << 3, e0 = eg << 2;
    const int sz  = (eg >> 1) & 3;          // per-edge swizzle key: ((e>>3)&3)
    const int em  = t >> 2, q = t & 3;      // ea gather: 4 threads/edge
    const int esz = (em >> 3) & 3;

    // ---- stage weights once ----
    w1L[t] = ((const float4*)(W1 + (size_t)IC * OC))[t];
    {   // W2 -> transposed bf16 hi/lo planes: W2t[n][k]
        const int n = t >> 2, kh = (t & 3) * 32;
        const int key = swzk(n) << 4;
        for (int j0 = 0; j0 < 32; j0 += 8) {
            union { unsigned short us[8]; uint4 qv; } Hh, Hl;
            #pragma unroll
            for (int j = 0; j < 8; ++j) {
                const float w = W2[(size_t)(kh + j0 + j) * OC + n];
                const unsigned short h = bf16u(w);
                Hh.us[j] = h;
                Hl.us[j] = bf16u(w - bf16tof(h));
            }
            const int a = n * 256 + (((kh + j0) * 2) ^ key);
            *(uint4*)(W2hi + a) = Hh.qv;
            *(uint4*)(W2lo + a) = Hl.qv;
        }
    }
    float b2r[8];
    #pragma unroll
    for (int nr = 0; nr < 8; ++nr) b2r[nr] = b2[nr * 16 + (l & 15)];

    const int nper = (E / EPB) / NBLK;          // 8 batches per block
    const int ibb  = blockIdx.x * nper;

    // prologue: idx(0) -> buffer 0; prefetch ea/xw for batch 0; idx(1) -> regs
    if (t < EPB) {
        const int2 rc = csr[(size_t)ibb * EPB + t];
        srowL[t] = rc.x;
        scolL[t] = rc.y;
    }
    __syncthreads();

    float4 pA;                                   // ea prefetch (batch cur)
    {
        const int r = srowL[em], c = scolL[em];
        pA = ((const float4*)(eattr + ((size_t)r * NN + c) * ED))[q];
    }
    float4 xa[4], xb[4];                         // xw prefetch (batch cur)
    #pragma unroll
    for (int ri = 0; ri < 4; ++ri) {
        const int row = srowL[e0 + ri];
        const float4* p = (const float4*)(xw1b + (size_t)row * OC + c0);
        xa[ri] = p[0]; xb[ri] = p[1];
    }
    int2 pidx;                                   // idx prefetch (batch cur+1)
    {
        const int ibn = (nper > 1) ? 1 : 0;
        pidx = (t < EPB) ? csr[(size_t)(ibb + ibn) * EPB + t] : make_int2(0, 0);
    }

    int cur = 0;
    for (int ii = 0; ii < nper; ++ii) {
        const int nxt = cur ^ 1;

        BAR();  // prev lacc flush done; srow[nxt] free for rewrite

        // zero lacc; write idx(ii+1) -> buffer nxt (from regs, no stall);
        // stage eaL <- prefetched reg
        lacc[t] = 0.f; lacc[t + NT] = 0.f;
        if (t < EPB) { srowL[nxt * 128 + t] = pidx.x; scolL[nxt * 128 + t] = pidx.y; }
        eaL[(em * 4 + q) ^ esz] = pA;
        BAR();  // eaL + srow[nxt] visible

        // layer 1 (f32): 4e x 8c per thread; xa/xb already in regs
        float4 ha[4], hb[4];
        #pragma unroll
        for (int ri = 0; ri < 4; ++ri) { ha[ri] = xa[ri]; hb[ri] = xb[ri]; }
        #pragma unroll
        for (int dc = 0; dc < 4; ++dc) {
            float4 ev[4];
            #pragma unroll
            for (int ri = 0; ri < 4; ++ri)
                ev[ri] = eaL[((e0 + ri) * 4 + dc) ^ sz];
            #pragma unroll
            for (int dd = 0; dd < 4; ++dd) {
                const int d = dc * 4 + dd;
                const float4 wA = w1L[d * 32 + cg * 2];
                const float4 wB = w1L[d * 32 + cg * 2 + 1];
                #pragma unroll
                for (int ri = 0; ri < 4; ++ri) {
                    const float evd = (dd == 0) ? ev[ri].x : (dd == 1) ? ev[ri].y
                                     : (dd == 2) ? ev[ri].z : ev[ri].w;
                    ha[ri].x = fmaf(evd, wA.x, ha[ri].x);
                    ha[ri].y = fmaf(evd, wA.y, ha[ri].y);
                    ha[ri].z = fmaf(evd, wA.z, ha[ri].z);
                    ha[ri].w = fmaf(evd, wA.w, ha[ri].w);
                    hb[ri].x = fmaf(evd, wB.x, hb[ri].x);
                    hb[ri].y = fmaf(evd, wB.y, hb[ri].y);
                    hb[ri].z = fmaf(evd, wB.z, hb[ri].z);
                    hb[ri].w = fmaf(evd, wB.w, hb[ri].w);
                }
            }
        }
        // relu + bf16 hi/lo split -> h1 planes
        #pragma unroll
        for (int ri = 0; ri < 4; ++ri) {
            const int row = e0 + ri;
            float v[8] = { ha[ri].x, ha[ri].y, ha[ri].z, ha[ri].w,
                           hb[ri].x, hb[ri].y, hb[ri].z, hb[ri].w };
            union { unsigned short us[8]; uint4 qv; } Hh, Hl;
            #pragma unroll
            for (int j = 0; j < 8; ++j) {
                const float f = fmaxf(v[j], 0.f);
                const unsigned short h = bf16u(f);
                Hh.us[j] = h;
                Hl.us[j] = bf16u(f - bf16tof(h));
            }
            const int boff = (cg * 16) ^ (swzk(row) << 4);
            *(uint4*)(h1hi + row * 256 + boff) = Hh.qv;
            *(uint4*)(h1lo + row * 256 + boff) = Hl.qv;
        }

        // prefetches for batch ii+1 (indices in buffer nxt) + idx(ii+2)
        {
            const int r = srowL[nxt * 128 + em], c = scolL[nxt * 128 + em];
            pA = ((const float4*)(eattr + ((size_t)r * NN + c) * ED))[q];
        }
        #pragma unroll
        for (int ri = 0; ri < 4; ++ri) {
            const int row = srowL[nxt * 128 + e0 + ri];
            const float4* p = (const float4*)(xw1b + (size_t)row * OC + c0);
            xa[ri] = p[0]; xb[ri] = p[1];
        }
        {
            const int iin = (ii + 2 < nper) ? (ii + 2) : (nper - 1);
            pidx = (t < EPB) ? csr[(size_t)(ibb + iin) * EPB + t] : make_int2(0, 0);
        }
        BAR();  // h1 planes visible

        // layer 2: 3-term split MFMA. Wave tile 16e x 128c.
        f32x4 acc[8];
        #pragma unroll
        for (int nr = 0; nr < 8; ++nr) acc[nr] = (f32x4){0.f, 0.f, 0.f, 0.f};
        const int arow = wid * 16 + (l & 15);
        const int akey = swzk(arow) << 4;
        #pragma unroll
        for (int kc = 0; kc < 4; ++kc) {
            const int kb = kc * 64 + ((l >> 4) << 4);      // byte offset in row
            const bf16x8 aH = *(const bf16x8*)(h1hi + arow * 256 + (kb ^ akey));
            const bf16x8 aL = *(const bf16x8*)(h1lo + arow * 256 + (kb ^ akey));
            #pragma unroll
            for (int nr = 0; nr < 8; ++nr) {
                const int brow = nr * 16 + (l & 15);
                const int ba = brow * 256 + (kb ^ (swzk(brow) << 4));
                const bf16x8 bH = *(const bf16x8*)(W2hi + ba);
                const bf16x8 bL = *(const bf16x8*)(W2lo + ba);
                acc[nr] = __builtin_amdgcn_mfma_f32_16x16x32_bf16(aH, bH, acc[nr], 0, 0, 0);
                acc[nr] = __builtin_amdgcn_mfma_f32_16x16x32_bf16(aL, bH, acc[nr], 0, 0, 0);
                acc[nr] = __builtin_amdgcn_mfma_f32_16x16x32_bf16(aH, bL, acc[nr], 0, 0, 0);
            }
        }

        // epilogue: D row = edge (lane>>4)*4+r, col = nr*16+(lane&15).
        const int colbase = scolL[cur * 128];
        {
            const int eb = wid * 16 + ((l >> 4) << 2);
            float s[8];
            int ccur = scolL[cur * 128 + eb];
            #pragma unroll
            for (int nr = 0; nr < 8; ++nr)
                s[nr] = fmaxf(acc[nr][0] + b2r[nr], 0.f);
            #pragma unroll
            for (int r = 1; r < 4; ++r) {
                const int c = scolL[cur * 128 + eb + r];
                if (c != ccur) {
                    const int slot = ccur - colbase;
                    if (slot < NSLOT) {
                        #pragma unroll
                        for (int nr = 0; nr < 8; ++nr)
                            if (s[nr] != 0.f)
                                atomicAdd(&lacc[slot * OC + nr * 16 + (l & 15)], s[nr]);
                    } else {
                        #pragma unroll
                        for (int nr = 0; nr < 8; ++nr)
                            if (s[nr] != 0.f)
                                atomicAdd(&out[(size_t)ccur * OC + nr * 16 + (l & 15)], s[nr]);
                    }
                    ccur = c;
                    #pragma unroll
                    for (int nr = 0; nr < 8; ++nr)
                        s[nr] = fmaxf(acc[nr][r] + b2r[nr], 0.f);
                } else {
                    #pragma unroll
                    for (int nr = 0; nr < 8; ++nr)
                        s[nr] += fmaxf(acc[nr][r] + b2r[nr], 0.f);
                }
            }
            {
                const int slot = ccur - colbase;
                if (slot < NSLOT) {
                    #pragma unroll
                    for (int nr = 0; nr < 8; ++nr)
                        if (s[nr] != 0.f)
                            atomicAdd(&lacc[slot * OC + nr * 16 + (l & 15)], s[nr]);
                } else {
                    #pragma unroll
                    for (int nr = 0; nr < 8; ++nr)
                        if (s[nr] != 0.f)
                            atomicAdd(&out[(size_t)ccur * OC + nr * 16 + (l & 15)], s[nr]);
                }
            }
        }
        BAR();  // lacc complete

        // flush lacc -> out (fire-and-forget atomics)
        int span = scolL[cur * 128 + 127] - colbase + 1;
        if (span > NSLOT) span = NSLOT;
        for (int idx = t; idx < span * OC; idx += NT) {
            const float v = lacc[idx];
            if (v != 0.f)
                atomicAdd(&out[(size_t)(colbase + (idx >> 7)) * OC + (idx & 127)], v);
        }
        cur = nxt;
    }
}

#define LDS_BYTES 153600

extern "C" void kernel_launch(void* const* d_in, const int* in_sizes, int n_in,
                              void* d_out, int out_size, void* d_ws, size_t ws_size,
                              hipStream_t stream) {
    const float* x    = (const float*)d_in[0];
    const int*   eidx = (const int*)d_in[1];
    const float* ea   = (const float*)d_in[2];
    const float* W1   = (const float*)d_in[3];
    const float* b1   = (const float*)d_in[4];
    const float* W2   = (const float*)d_in[5];
    const float* b2   = (const float*)d_in[6];
    float* out = (float*)d_out;

    const int E = in_sizes[1] / 2;

    char* ws = (char*)d_ws;
    float* xw1b   = (float*)ws;                        // 2 MB
    int*   hist   = (int*)(ws + 2097152);              // 16 KB
    int*   cursor = (int*)(ws + 2097152 + 16384);      // 16 KB
    int2*  csr    = (int2*)(ws + 2097152 + 32768);     // 2 MB

    k_xw1<<<NN / 8, 128, 0, stream>>>(x, W1, b1, xw1b, out, hist);
    k_hist<<<(E + 255) / 256, 256, 0, stream>>>(eidx, hist, E);
    k_scan<<<1, 256, 0, stream>>>(hist, cursor);
    k_scatter<<<(E + 255) / 256, 256, 0, stream>>>(eidx, cursor, csr, E);

    hipFuncSetAttribute(reinterpret_cast<const void*>(k_edge6),
                        hipFuncAttributeMaxDynamicSharedMemorySize, LDS_BYTES);
    k_edge6<<<NBLK, NT, LDS_BYTES, stream>>>(csr, ea, xw1b, W1, W2, b2, out, E);
}

// Round 8
// 150.380 us; speedup vs baseline: 6.5109x; 1.0080x over previous
//
#include <hip/hip_runtime.h>
#include <hip/hip_bf16.h>

#define NN 4096
#define IC 128
#define OC 128
#define ED 16
#define EPB 128
#define NT 512
#define NSLOT 8
#define NBLK 256

typedef __bf16 bf16x8 __attribute__((ext_vector_type(8)));
typedef float  f32x16 __attribute__((ext_vector_type(16)));

// raw barrier: drain LDS ops only; global loads/atomics stay in flight
#define BAR() do { asm volatile("s_waitcnt lgkmcnt(0)" ::: "memory"); \
    __builtin_amdgcn_s_barrier(); \
    __builtin_amdgcn_sched_barrier(0); } while (0)

__device__ __forceinline__ unsigned short bf16u(float f) {   // RNE f32->bf16
    unsigned int u = __float_as_uint(f);
    u = (u + 0x7FFFu + ((u >> 16) & 1u)) >> 16;
    return (unsigned short)u;
}
__device__ __forceinline__ float bf16tof(unsigned short h) {
    return __uint_as_float(((unsigned int)h) << 16);
}
__device__ __forceinline__ int swzk(int row) { return (row ^ (row >> 3)) & 7; }

// ---- Phase 1: xw1b = x@W1[:128] + b1; also zeroes out + hist (fused) ----
__global__ __launch_bounds__(128) void k_xw1(
    const float* __restrict__ x, const float* __restrict__ W1,
    const float* __restrict__ b1, float* __restrict__ xw1b,
    float* __restrict__ out, int* __restrict__ hist)
{
    __shared__ float xs[8][IC];
    const int t = threadIdx.x;
    const int r0 = blockIdx.x * 8;
    #pragma unroll
    for (int r = 0; r < 8; ++r) xs[r][t] = x[(size_t)(r0 + r) * IC + t];

    const float4 z = make_float4(0.f, 0.f, 0.f, 0.f);
    float4* o4 = (float4*)out;
    o4[blockIdx.x * 256 + t]       = z;
    o4[blockIdx.x * 256 + 128 + t] = z;
    if (blockIdx.x == 0) {
        int4* h4 = (int4*)hist;
        #pragma unroll
        for (int j = 0; j < 8; ++j) h4[j * 128 + t] = make_int4(0, 0, 0, 0);
    }

    __syncthreads();
    float acc[8];
    const float bb = b1[t];
    #pragma unroll
    for (int r = 0; r < 8; ++r) acc[r] = bb;
    #pragma unroll 4
    for (int k = 0; k < IC; ++k) {
        const float w = W1[(size_t)k * OC + t];
        #pragma unroll
        for (int r = 0; r < 8; ++r) acc[r] = fmaf(xs[r][k], w, acc[r]);
    }
    #pragma unroll
    for (int r = 0; r < 8; ++r) xw1b[(size_t)(r0 + r) * OC + t] = acc[r];
}

// ---------------- CSR build: hist -> scan -> scatter ----------------------
__global__ void k_hist(const int* __restrict__ eidx, int* __restrict__ hist, int E) {
    const int i = blockIdx.x * blockDim.x + threadIdx.x;
    if (i < E) atomicAdd(&hist[eidx[E + i]], 1);
}

__global__ __launch_bounds__(256) void k_scan(
    const int* __restrict__ hist, int* __restrict__ cursor)
{
    __shared__ int tot[256];
    __shared__ int base[256];
    const int t = threadIdx.x;
    int loc[16];
    int s = 0;
    #pragma unroll
    for (int j = 0; j < 16; ++j) { loc[j] = s; s += hist[t * 16 + j]; }
    tot[t] = s;
    __syncthreads();
    if (t == 0) {
        int a = 0;
        for (int i = 0; i < 256; ++i) { base[i] = a; a += tot[i]; }
    }
    __syncthreads();
    const int b = base[t];
    #pragma unroll
    for (int j = 0; j < 16; ++j) cursor[t * 16 + j] = b + loc[j];
}

__global__ void k_scatter(const int* __restrict__ eidx, int* __restrict__ cursor,
                          int2* __restrict__ csr, int E) {
    const int i = blockIdx.x * blockDim.x + threadIdx.x;
    if (i < E) {
        const int row = eidx[i];
        const int col = eidx[E + i];
        const int pos = atomicAdd(&cursor[col], 1);
        csr[pos] = make_int2(row, col);
    }
}

// ---------------- Phase 2: CSR batches, 32x32 MFMA, W2 in registers ------
// 256 persistent blocks (1/CU), 8 waves (2/SIMD). W2 hi/lo bf16 fragments
// live in 64 VGPR per thread (batch-invariant; loaded once) -> layer-2 B
// operand costs ZERO LDS traffic (was 8x-redundant 576KB/batch/CU).
// Layer 2: mfma_f32_32x32x16_bf16, wave = 1 n-tile (32c) x 2 m-tiles (32e).
// LDS 88KB: h1 planes 64KB + eaL/w1L/lacc/idx.
__global__ __launch_bounds__(NT, 2) void k_edge7(
    const int2* __restrict__ csr, const float* __restrict__ eattr,
    const float* __restrict__ xw1b, const float* __restrict__ W1,
    const float* __restrict__ W2, const float* __restrict__ b2,
    float* __restrict__ out, int E)
{
    extern __shared__ char smem[];
    char*   const h1hi = smem;                      // 32KB bf16 [128e][128k] swz
    char*   const h1lo = smem + 32768;              // 32KB
    float4* const eaL  = (float4*)(smem + 65536);   // [512] swz (8KB)
    float4* const w1L  = (float4*)(smem + 73728);   // [512] (8KB)
    float*  const lacc = (float*)(smem + 81920);    // [8][128] (4KB)
    int*    const srowL = (int*)(smem + 86016);     // [2][128]
    int*    const scolL = srowL + 256;              // [2][128]

    const int t   = threadIdx.x;
    const int l   = t & 63;
    const int wid = t >> 6;                 // 8 waves
    const int cg  = t & 15, eg = t >> 4;    // layer-1 tile: 4e x 8c
    const int c0  = cg << 3, e0 = eg << 2;
    const int sz  = (eg >> 1) & 3;
    const int em  = t >> 2, q = t & 3;      // ea gather: 4 threads/edge
    const int esz = (em >> 3) & 3;

    // layer-2 wave mapping: n-tile = wid&3 (32 cols), m-half = wid>>2
    const int ntl = wid & 3;
    const int mh  = wid >> 2;
    const int lm  = l & 31;
    const int hi  = l >> 5;
    const int c2  = ntl * 32 + lm;          // this lane's output channel

    // ---- stage w1L (edge-part of W1) ----
    w1L[t] = ((const float4*)(W1 + (size_t)IC * OC))[t];

    // ---- W2 -> REGISTER hi/lo fragments (batch-invariant, 64 VGPR) ----
    // B-frag for 32x32x16: lane holds col=c2, k = s*16 + hi*8 + j
    bf16x8 w2h[8], w2l[8];
    #pragma unroll
    for (int s = 0; s < 8; ++s) {
        union { unsigned short us[8]; bf16x8 v; } Uh, Ul;
        #pragma unroll
        for (int j = 0; j < 8; ++j) {
            const float w = W2[(size_t)(s * 16 + hi * 8 + j) * OC + c2];
            const unsigned short h = bf16u(w);
            Uh.us[j] = h;
            Ul.us[j] = bf16u(w - bf16tof(h));
        }
        w2h[s] = Uh.v; w2l[s] = Ul.v;
    }
    const float b2s = b2[c2];

    // zero lacc once (afterwards the flush self-zeroes)
    lacc[t] = 0.f; lacc[t + NT] = 0.f;

    const int nper = (E / EPB) / NBLK;      // 8 batches per block
    const int ibb  = blockIdx.x * nper;

    if (t < EPB) {
        const int2 rc = csr[(size_t)ibb * EPB + t];
        srowL[t] = rc.x;
        scolL[t] = rc.y;
    }
    __syncthreads();

    float4 pA;                               // ea prefetch (batch cur)
    {
        const int r = srowL[em], c = scolL[em];
        pA = ((const float4*)(eattr + ((size_t)r * NN + c) * ED))[q];
    }
    int2 pidx;                               // idx prefetch (batch cur+1)
    {
        const int ibn = (nper > 1) ? 1 : 0;
        pidx = (t < EPB) ? csr[(size_t)(ibb + ibn) * EPB + t] : make_int2(0, 0);
    }

    int cur = 0;
    for (int ii = 0; ii < nper; ++ii) {
        const int nxt = cur ^ 1;

        BAR();  // prev flush done; srow[nxt] free

        // stage: idx(ii+1) -> buffer nxt (regs), eaL <- prefetched reg,
        // issue xw loads (consumed after barrier; stay in flight)
        if (t < EPB) { srowL[nxt * 128 + t] = pidx.x; scolL[nxt * 128 + t] = pidx.y; }
        eaL[(em * 4 + q) ^ esz] = pA;
        float4 xa[4], xb[4];
        #pragma unroll
        for (int ri = 0; ri < 4; ++ri) {
            const int row = srowL[cur * 128 + e0 + ri];
            const float4* p = (const float4*)(xw1b + (size_t)row * OC + c0);
            xa[ri] = p[0]; xb[ri] = p[1];
        }
        BAR();  // eaL + srow[nxt] visible

        // layer 1 (f32): 4e x 8c per thread
        float4 ha[4], hb[4];
        #pragma unroll
        for (int ri = 0; ri < 4; ++ri) { ha[ri] = xa[ri]; hb[ri] = xb[ri]; }
        #pragma unroll
        for (int dc = 0; dc < 4; ++dc) {
            float4 ev[4];
            #pragma unroll
            for (int ri = 0; ri < 4; ++ri)
                ev[ri] = eaL[((e0 + ri) * 4 + dc) ^ sz];
            #pragma unroll
            for (int dd = 0; dd < 4; ++dd) {
                const int d = dc * 4 + dd;
                const float4 wA = w1L[d * 32 + cg * 2];
                const float4 wB = w1L[d * 32 + cg * 2 + 1];
                #pragma unroll
                for (int ri = 0; ri < 4; ++ri) {
                    const float evd = (dd == 0) ? ev[ri].x : (dd == 1) ? ev[ri].y
                                     : (dd == 2) ? ev[ri].z : ev[ri].w;
                    ha[ri].x = fmaf(evd, wA.x, ha[ri].x);
                    ha[ri].y = fmaf(evd, wA.y, ha[ri].y);
                    ha[ri].z = fmaf(evd, wA.z, ha[ri].z);
                    ha[ri].w = fmaf(evd, wA.w, ha[ri].w);
                    hb[ri].x = fmaf(evd, wB.x, hb[ri].x);
                    hb[ri].y = fmaf(evd, wB.y, hb[ri].y);
                    hb[ri].z = fmaf(evd, wB.z, hb[ri].z);
                    hb[ri].w = fmaf(evd, wB.w, hb[ri].w);
                }
            }
        }
        // relu + bf16 hi/lo split -> h1 planes
        #pragma unroll
        for (int ri = 0; ri < 4; ++ri) {
            const int row = e0 + ri;
            float v[8] = { ha[ri].x, ha[ri].y, ha[ri].z, ha[ri].w,
                           hb[ri].x, hb[ri].y, hb[ri].z, hb[ri].w };
            union { unsigned short us[8]; uint4 qv; } Hh, Hl;
            #pragma unroll
            for (int j = 0; j < 8; ++j) {
                const float f = fmaxf(v[j], 0.f);
                const unsigned short h = bf16u(f);
                Hh.us[j] = h;
                Hl.us[j] = bf16u(f - bf16tof(h));
            }
            const int boff = (cg * 16) ^ (swzk(row) << 4);
            *(uint4*)(h1hi + row * 256 + boff) = Hh.qv;
            *(uint4*)(h1lo + row * 256 + boff) = Hl.qv;
        }
        // prefetch next batch ea + idx(ii+2)
        {
            const int r = srowL[nxt * 128 + em], c = scolL[nxt * 128 + em];
            pA = ((const float4*)(eattr + ((size_t)r * NN + c) * ED))[q];
        }
        {
            const int iin = (ii + 2 < nper) ? (ii + 2) : (nper - 1);
            pidx = (t < EPB) ? csr[(size_t)(ibb + iin) * EPB + t] : make_int2(0, 0);
        }
        BAR();  // h1 planes visible

        // layer 2: 32x32x16 MFMA, 3-term split, B from registers.
        // A-frag: lane holds row=arow, k = s*16 + hi*8 + j  (16B read)
        f32x16 acc0 = (f32x16)(0.0f);
        f32x16 acc1 = (f32x16)(0.0f);
        const int arow0 = (mh * 2 + 0) * 32 + lm;
        const int arow1 = (mh * 2 + 1) * 32 + lm;
        const int ak0 = swzk(arow0) << 4;
        const int ak1 = swzk(arow1) << 4;
        #pragma unroll
        for (int s = 0; s < 8; ++s) {
            const int kb = s * 32 + hi * 16;
            const bf16x8 aH0 = *(const bf16x8*)(h1hi + arow0 * 256 + (kb ^ ak0));
            const bf16x8 aL0 = *(const bf16x8*)(h1lo + arow0 * 256 + (kb ^ ak0));
            const bf16x8 aH1 = *(const bf16x8*)(h1hi + arow1 * 256 + (kb ^ ak1));
            const bf16x8 aL1 = *(const bf16x8*)(h1lo + arow1 * 256 + (kb ^ ak1));
            acc0 = __builtin_amdgcn_mfma_f32_32x32x16_bf16(aH0, w2h[s], acc0, 0, 0, 0);
            acc1 = __builtin_amdgcn_mfma_f32_32x32x16_bf16(aH1, w2h[s], acc1, 0, 0, 0);
            acc0 = __builtin_amdgcn_mfma_f32_32x32x16_bf16(aL0, w2h[s], acc0, 0, 0, 0);
            acc1 = __builtin_amdgcn_mfma_f32_32x32x16_bf16(aL1, w2h[s], acc1, 0, 0, 0);
            acc0 = __builtin_amdgcn_mfma_f32_32x32x16_bf16(aH0, w2l[s], acc0, 0, 0, 0);
            acc1 = __builtin_amdgcn_mfma_f32_32x32x16_bf16(aH1, w2l[s], acc1, 0, 0, 0);
        }

        // epilogue: C layout col=lane&31, row=(reg&3)+8*(reg>>2)+4*(lane>>5).
        // reg group g: 4 consecutive edges -> scalar run-combine per lane.
        const int colbase = scolL[cur * 128];
        #pragma unroll
        for (int p = 0; p < 2; ++p) {
            const int mbase = (mh * 2 + p) * 32 + 4 * hi;
            #pragma unroll
            for (int g = 0; g < 4; ++g) {
                const int eb = mbase + 8 * g;
                float sv;
                {
                    const float a0 = (p == 0) ? acc0[4 * g] : acc1[4 * g];
                    sv = fmaxf(a0 + b2s, 0.f);
                }
                int ccur = scolL[cur * 128 + eb];
                #pragma unroll
                for (int j = 1; j < 4; ++j) {
                    const float aj = (p == 0) ? acc0[4 * g + j] : acc1[4 * g + j];
                    const float v = fmaxf(aj + b2s, 0.f);
                    const int c = scolL[cur * 128 + eb + j];
                    if (c == ccur) {
                        sv += v;
                    } else {
                        const int slot = ccur - colbase;
                        if (slot < NSLOT) {
                            if (sv != 0.f) atomicAdd(&lacc[slot * OC + c2], sv);
                        } else {
                            if (sv != 0.f) atomicAdd(&out[(size_t)ccur * OC + c2], sv);
                        }
                        ccur = c; sv = v;
                    }
                }
                const int slot = ccur - colbase;
                if (slot < NSLOT) {
                    if (sv != 0.f) atomicAdd(&lacc[slot * OC + c2], sv);
                } else {
                    if (sv != 0.f) atomicAdd(&out[(size_t)ccur * OC + c2], sv);
                }
            }
        }
        BAR();  // lacc complete

        // flush lacc -> out (fire-and-forget atomics) + self-zero
        int span = scolL[cur * 128 + 127] - colbase + 1;
        if (span > NSLOT) span = NSLOT;
        for (int idx = t; idx < span * OC; idx += NT) {
            const float v = lacc[idx];
            lacc[idx] = 0.f;
            if (v != 0.f)
                atomicAdd(&out[(size_t)(colbase + (idx >> 7)) * OC + (idx & 127)], v);
        }
        cur = nxt;
    }
}

#define LDS_BYTES 88064

extern "C" void kernel_launch(void* const* d_in, const int* in_sizes, int n_in,
                              void* d_out, int out_size, void* d_ws, size_t ws_size,
                              hipStream_t stream) {
    const float* x    = (const float*)d_in[0];
    const int*   eidx = (const int*)d_in[1];
    const float* ea   = (const float*)d_in[2];
    const float* W1   = (const float*)d_in[3];
    const float* b1   = (const float*)d_in[4];
    const float* W2   = (const float*)d_in[5];
    const float* b2   = (const float*)d_in[6];
    float* out = (float*)d_out;

    const int E = in_sizes[1] / 2;

    char* ws = (char*)d_ws;
    float* xw1b   = (float*)ws;                        // 2 MB
    int*   hist   = (int*)(ws + 2097152);              // 16 KB
    int*   cursor = (int*)(ws + 2097152 + 16384);      // 16 KB
    int2*  csr    = (int2*)(ws + 2097152 + 32768);     // 2 MB

    k_xw1<<<NN / 8, 128, 0, stream>>>(x, W1, b1, xw1b, out, hist);
    k_hist<<<(E + 255) / 256, 256, 0, stream>>>(eidx, hist, E);
    k_scan<<<1, 256, 0, stream>>>(hist, cursor);
    k_scatter<<<(E + 255) / 256, 256, 0, stream>>>(eidx, cursor, csr, E);

    hipFuncSetAttribute(reinterpret_cast<const void*>(k_edge7),
                        hipFuncAttributeMaxDynamicSharedMemorySize, LDS_BYTES);
    k_edge7<<<NBLK, NT, LDS_BYTES, stream>>>(csr, ea, xw1b, W1, W2, b2, out, E);
}

// Round 10
// 138.803 us; speedup vs baseline: 7.0539x; 1.0834x over previous
//
#include <hip/hip_runtime.h>
#include <hip/hip_bf16.h>

#define NN 4096
#define IC 128
#define OC 128
#define ED 16
#define EPB 128
#define NT 512
#define NSLOT 8
#define NBLK 256
#define NCPY 8

typedef __bf16 bf16x8 __attribute__((ext_vector_type(8)));
typedef float  f32x16 __attribute__((ext_vector_type(16)));

// raw barrier: drain LDS ops only; global loads/atomics stay in flight
#define BAR() do { asm volatile("s_waitcnt lgkmcnt(0)" ::: "memory"); \
    __builtin_amdgcn_s_barrier(); \
    __builtin_amdgcn_sched_barrier(0); } while (0)

__device__ __forceinline__ unsigned short bf16u(float f) {   // RNE f32->bf16
    unsigned int u = __float_as_uint(f);
    u = (u + 0x7FFFu + ((u >> 16) & 1u)) >> 16;
    return (unsigned short)u;
}
__device__ __forceinline__ float bf16tof(unsigned short h) {
    return __uint_as_float(((unsigned int)h) << 16);
}
__device__ __forceinline__ int swzk(int row) { return (row ^ (row >> 3)) & 7; }

// ---- Phase 1: xw1b = x@W1[:128] + b1; zeroes out + hist8 (fused) ----
__global__ __launch_bounds__(128) void k_xw1(
    const float* __restrict__ x, const float* __restrict__ W1,
    const float* __restrict__ b1, float* __restrict__ xw1b,
    float* __restrict__ out, int* __restrict__ hist8)
{
    __shared__ float xs[8][IC];
    const int t = threadIdx.x;
    const int r0 = blockIdx.x * 8;
    #pragma unroll
    for (int r = 0; r < 8; ++r) xs[r][t] = x[(size_t)(r0 + r) * IC + t];

    const float4 z = make_float4(0.f, 0.f, 0.f, 0.f);
    float4* o4 = (float4*)out;
    o4[blockIdx.x * 256 + t]       = z;
    o4[blockIdx.x * 256 + 128 + t] = z;
    if (blockIdx.x < NCPY) {       // zero one 4096-int histogram copy each
        int4* h4 = (int4*)(hist8 + blockIdx.x * 4096);
        #pragma unroll
        for (int j = 0; j < 8; ++j) h4[j * 128 + t] = make_int4(0, 0, 0, 0);
    }

    __syncthreads();
    float acc[8];
    const float bb = b1[t];
    #pragma unroll
    for (int r = 0; r < 8; ++r) acc[r] = bb;
    #pragma unroll 4
    for (int k = 0; k < IC; ++k) {
        const float w = W1[(size_t)k * OC + t];
        #pragma unroll
        for (int r = 0; r < 8; ++r) acc[r] = fmaf(xs[r][k], w, acc[r]);
    }
    #pragma unroll
    for (int r = 0; r < 8; ++r) xw1b[(size_t)(r0 + r) * OC + t] = acc[r];
}

// -------- CSR build, 8-replica (contention-free-ish) ----------------------
// hist/cursor replicated 8x; block -> copy blockIdx&7. Same mapping in hist
// and scatter => per-(copy,bin) counts consistent; scan pre-reserves a range
// per (bin, copy) so scatter atomics only contend within one copy (8x less,
// spread over 128KB of L2 instead of 16KB).
__global__ void k_hist(const int* __restrict__ eidx, int* __restrict__ hist8, int E) {
    const int i = blockIdx.x * blockDim.x + threadIdx.x;
    const int k = blockIdx.x & (NCPY - 1);
    if (i < E) atomicAdd(&hist8[k * 4096 + eidx[E + i]], 1);
}

__global__ __launch_bounds__(256) void k_scan(
    const int* __restrict__ hist8, int* __restrict__ cursor8)
{
    __shared__ int tot[256];
    __shared__ int base[256];
    const int t = threadIdx.x;
    int loc[16];
    int s = 0;
    #pragma unroll
    for (int j = 0; j < 16; ++j) {
        const int b = t * 16 + j;
        int sb = 0;
        #pragma unroll
        for (int k = 0; k < NCPY; ++k) sb += hist8[k * 4096 + b];
        loc[j] = s; s += sb;
    }
    tot[t] = s;
    __syncthreads();
    if (t == 0) {
        int a = 0;
        for (int i = 0; i < 256; ++i) { base[i] = a; a += tot[i]; }
    }
    __syncthreads();
    const int a = base[t];
    #pragma unroll
    for (int j = 0; j < 16; ++j) {
        const int b = t * 16 + j;
        int off = a + loc[j];
        #pragma unroll
        for (int k = 0; k < NCPY; ++k) {
            cursor8[k * 4096 + b] = off;
            off += hist8[k * 4096 + b];
        }
    }
}

__global__ void k_scatter(const int* __restrict__ eidx, int* __restrict__ cursor8,
                          int2* __restrict__ csr, int E) {
    const int i = blockIdx.x * blockDim.x + threadIdx.x;
    const int k = blockIdx.x & (NCPY - 1);
    if (i < E) {
        const int row = eidx[i];
        const int col = eidx[E + i];
        const int pos = atomicAdd(&cursor8[k * 4096 + col], 1);
        csr[pos] = make_int2(row, col);
    }
}

// ---------------- Phase 2: CSR batches, 32x32 MFMA, W2 in registers ------
// (unchanged from round 8)
__global__ __launch_bounds__(NT, 2) void k_edge7(
    const int2* __restrict__ csr, const float* __restrict__ eattr,
    const float* __restrict__ xw1b, const float* __restrict__ W1,
    const float* __restrict__ W2, const float* __restrict__ b2,
    float* __restrict__ out, int E)
{
    extern __shared__ char smem[];
    char*   const h1hi = smem;                      // 32KB bf16 [128e][128k] swz
    char*   const h1lo = smem + 32768;              // 32KB
    float4* const eaL  = (float4*)(smem + 65536);   // [512] swz (8KB)
    float4* const w1L  = (float4*)(smem + 73728);   // [512] (8KB)
    float*  const lacc = (float*)(smem + 81920);    // [8][128] (4KB)
    int*    const srowL = (int*)(smem + 86016);     // [2][128]
    int*    const scolL = srowL + 256;              // [2][128]

    const int t   = threadIdx.x;
    const int l   = t & 63;
    const int wid = t >> 6;                 // 8 waves
    const int cg  = t & 15, eg = t >> 4;    // layer-1 tile: 4e x 8c
    const int c0  = cg << 3, e0 = eg << 2;
    const int sz  = (eg >> 1) & 3;
    const int em  = t >> 2, q = t & 3;      // ea gather: 4 threads/edge
    const int esz = (em >> 3) & 3;

    const int ntl = wid & 3;
    const int mh  = wid >> 2;
    const int lm  = l & 31;
    const int hi  = l >> 5;
    const int c2  = ntl * 32 + lm;          // this lane's output channel

    w1L[t] = ((const float4*)(W1 + (size_t)IC * OC))[t];

    // W2 -> register hi/lo fragments (batch-invariant, 64 VGPR)
    bf16x8 w2h[8], w2l[8];
    #pragma unroll
    for (int s = 0; s < 8; ++s) {
        union { unsigned short us[8]; bf16x8 v; } Uh, Ul;
        #pragma unroll
        for (int j = 0; j < 8; ++j) {
            const float w = W2[(size_t)(s * 16 + hi * 8 + j) * OC + c2];
            const unsigned short h = bf16u(w);
            Uh.us[j] = h;
            Ul.us[j] = bf16u(w - bf16tof(h));
        }
        w2h[s] = Uh.v; w2l[s] = Ul.v;
    }
    const float b2s = b2[c2];

    lacc[t] = 0.f; lacc[t + NT] = 0.f;

    const int nper = (E / EPB) / NBLK;      // 8 batches per block
    const int ibb  = blockIdx.x * nper;

    if (t < EPB) {
        const int2 rc = csr[(size_t)ibb * EPB + t];
        srowL[t] = rc.x;
        scolL[t] = rc.y;
    }
    __syncthreads();

    float4 pA;                               // ea prefetch (batch cur)
    {
        const int r = srowL[em], c = scolL[em];
        pA = ((const float4*)(eattr + ((size_t)r * NN + c) * ED))[q];
    }
    int2 pidx;                               // idx prefetch (batch cur+1)
    {
        const int ibn = (nper > 1) ? 1 : 0;
        pidx = (t < EPB) ? csr[(size_t)(ibb + ibn) * EPB + t] : make_int2(0, 0);
    }

    int cur = 0;
    for (int ii = 0; ii < nper; ++ii) {
        const int nxt = cur ^ 1;

        BAR();  // prev flush done; srow[nxt] free

        if (t < EPB) { srowL[nxt * 128 + t] = pidx.x; scolL[nxt * 128 + t] = pidx.y; }
        eaL[(em * 4 + q) ^ esz] = pA;
        float4 xa[4], xb[4];
        #pragma unroll
        for (int ri = 0; ri < 4; ++ri) {
            const int row = srowL[cur * 128 + e0 + ri];
            const float4* p = (const float4*)(xw1b + (size_t)row * OC + c0);
            xa[ri] = p[0]; xb[ri] = p[1];
        }
        BAR();  // eaL + srow[nxt] visible

        // layer 1 (f32): 4e x 8c per thread
        float4 ha[4], hb[4];
        #pragma unroll
        for (int ri = 0; ri < 4; ++ri) { ha[ri] = xa[ri]; hb[ri] = xb[ri]; }
        #pragma unroll
        for (int dc = 0; dc < 4; ++dc) {
            float4 ev[4];
            #pragma unroll
            for (int ri = 0; ri < 4; ++ri)
                ev[ri] = eaL[((e0 + ri) * 4 + dc) ^ sz];
            #pragma unroll
            for (int dd = 0; dd < 4; ++dd) {
                const int d = dc * 4 + dd;
                const float4 wA = w1L[d * 32 + cg * 2];
                const float4 wB = w1L[d * 32 + cg * 2 + 1];
                #pragma unroll
                for (int ri = 0; ri < 4; ++ri) {
                    const float evd = (dd == 0) ? ev[ri].x : (dd == 1) ? ev[ri].y
                                     : (dd == 2) ? ev[ri].z : ev[ri].w;
                    ha[ri].x = fmaf(evd, wA.x, ha[ri].x);
                    ha[ri].y = fmaf(evd, wA.y, ha[ri].y);
                    ha[ri].z = fmaf(evd, wA.z, ha[ri].z);
                    ha[ri].w = fmaf(evd, wA.w, ha[ri].w);
                    hb[ri].x = fmaf(evd, wB.x, hb[ri].x);
                    hb[ri].y = fmaf(evd, wB.y, hb[ri].y);
                    hb[ri].z = fmaf(evd, wB.z, hb[ri].z);
                    hb[ri].w = fmaf(evd, wB.w, hb[ri].w);
                }
            }
        }
        #pragma unroll
        for (int ri = 0; ri < 4; ++ri) {
            const int row = e0 + ri;
            float v[8] = { ha[ri].x, ha[ri].y, ha[ri].z, ha[ri].w,
                           hb[ri].x, hb[ri].y, hb[ri].z, hb[ri].w };
            union { unsigned short us[8]; uint4 qv; } Hh, Hl;
            #pragma unroll
            for (int j = 0; j < 8; ++j) {
                const float f = fmaxf(v[j], 0.f);
                const unsigned short h = bf16u(f);
                Hh.us[j] = h;
                Hl.us[j] = bf16u(f - bf16tof(h));
            }
            const int boff = (cg * 16) ^ (swzk(row) << 4);
            *(uint4*)(h1hi + row * 256 + boff) = Hh.qv;
            *(uint4*)(h1lo + row * 256 + boff) = Hl.qv;
        }
        {
            const int r = srowL[nxt * 128 + em], c = scolL[nxt * 128 + em];
            pA = ((const float4*)(eattr + ((size_t)r * NN + c) * ED))[q];
        }
        {
            const int iin = (ii + 2 < nper) ? (ii + 2) : (nper - 1);
            pidx = (t < EPB) ? csr[(size_t)(ibb + iin) * EPB + t] : make_int2(0, 0);
        }
        BAR();  // h1 planes visible

        // layer 2: 32x32x16 MFMA, 3-term split, B from registers
        f32x16 acc0 = (f32x16)(0.0f);
        f32x16 acc1 = (f32x16)(0.0f);
        const int arow0 = (mh * 2 + 0) * 32 + lm;
        const int arow1 = (mh * 2 + 1) * 32 + lm;
        const int ak0 = swzk(arow0) << 4;
        const int ak1 = swzk(arow1) << 4;
        #pragma unroll
        for (int s = 0; s < 8; ++s) {
            const int kb = s * 32 + hi * 16;
            const bf16x8 aH0 = *(const bf16x8*)(h1hi + arow0 * 256 + (kb ^ ak0));
            const bf16x8 aL0 = *(const bf16x8*)(h1lo + arow0 * 256 + (kb ^ ak0));
            const bf16x8 aH1 = *(const bf16x8*)(h1hi + arow1 * 256 + (kb ^ ak1));
            const bf16x8 aL1 = *(const bf16x8*)(h1lo + arow1 * 256 + (kb ^ ak1));
            acc0 = __builtin_amdgcn_mfma_f32_32x32x16_bf16(aH0, w2h[s], acc0, 0, 0, 0);
            acc1 = __builtin_amdgcn_mfma_f32_32x32x16_bf16(aH1, w2h[s], acc1, 0, 0, 0);
            acc0 = __builtin_amdgcn_mfma_f32_32x32x16_bf16(aL0, w2h[s], acc0, 0, 0, 0);
            acc1 = __builtin_amdgcn_mfma_f32_32x32x16_bf16(aL1, w2h[s], acc1, 0, 0, 0);
            acc0 = __builtin_amdgcn_mfma_f32_32x32x16_bf16(aH0, w2l[s], acc0, 0, 0, 0);
            acc1 = __builtin_amdgcn_mfma_f32_32x32x16_bf16(aH1, w2l[s], acc1, 0, 0, 0);
        }

        // epilogue: C layout col=lane&31, row=(reg&3)+8*(reg>>2)+4*(lane>>5)
        const int colbase = scolL[cur * 128];
        #pragma unroll
        for (int p = 0; p < 2; ++p) {
            const int mbase = (mh * 2 + p) * 32 + 4 * hi;
            #pragma unroll
            for (int g = 0; g < 4; ++g) {
                const int eb = mbase + 8 * g;
                float sv;
                {
                    const float a0 = (p == 0) ? acc0[4 * g] : acc1[4 * g];
                    sv = fmaxf(a0 + b2s, 0.f);
                }
                int ccur = scolL[cur * 128 + eb];
                #pragma unroll
                for (int j = 1; j < 4; ++j) {
                    const float aj = (p == 0) ? acc0[4 * g + j] : acc1[4 * g + j];
                    const float v = fmaxf(aj + b2s, 0.f);
                    const int c = scolL[cur * 128 + eb + j];
                    if (c == ccur) {
                        sv += v;
                    } else {
                        const int slot = ccur - colbase;
                        if (slot < NSLOT) {
                            if (sv != 0.f) atomicAdd(&lacc[slot * OC + c2], sv);
                        } else {
                            if (sv != 0.f) atomicAdd(&out[(size_t)ccur * OC + c2], sv);
                        }
                        ccur = c; sv = v;
                    }
                }
                const int slot = ccur - colbase;
                if (slot < NSLOT) {
                    if (sv != 0.f) atomicAdd(&lacc[slot * OC + c2], sv);
                } else {
                    if (sv != 0.f) atomicAdd(&out[(size_t)ccur * OC + c2], sv);
                }
            }
        }
        BAR();  // lacc complete

        int span = scolL[cur * 128 + 127] - colbase + 1;
        if (span > NSLOT) span = NSLOT;
        for (int idx = t; idx < span * OC; idx += NT) {
            const float v = lacc[idx];
            lacc[idx] = 0.f;
            if (v != 0.f)
                atomicAdd(&out[(size_t)(colbase + (idx >> 7)) * OC + (idx & 127)], v);
        }
        cur = nxt;
    }
}

#define LDS_BYTES 88064

extern "C" void kernel_launch(void* const* d_in, const int* in_sizes, int n_in,
                              void* d_out, int out_size, void* d_ws, size_t ws_size,
                              hipStream_t stream) {
    const float* x    = (const float*)d_in[0];
    const int*   eidx = (const int*)d_in[1];
    const float* ea   = (const float*)d_in[2];
    const float* W1   = (const float*)d_in[3];
    const float* b1   = (const float*)d_in[4];
    const float* W2   = (const float*)d_in[5];
    const float* b2   = (const float*)d_in[6];
    float* out = (float*)d_out;

    const int E = in_sizes[1] / 2;

    char* ws = (char*)d_ws;
    float* xw1b    = (float*)ws;                         // 2 MB
    int*   hist8   = (int*)(ws + 2097152);               // 8x16KB = 128 KB
    int*   cursor8 = (int*)(ws + 2097152 + 131072);      // 128 KB
    int2*  csr     = (int2*)(ws + 2097152 + 262144);     // 2 MB

    k_xw1<<<NN / 8, 128, 0, stream>>>(x, W1, b1, xw1b, out, hist8);
    k_hist<<<(E + 255) / 256, 256, 0, stream>>>(eidx, hist8, E);
    k_scan<<<1, 256, 0, stream>>>(hist8, cursor8);
    k_scatter<<<(E + 255) / 256, 256, 0, stream>>>(eidx, cursor8, csr, E);

    hipFuncSetAttribute(reinterpret_cast<const void*>(k_edge7),
                        hipFuncAttributeMaxDynamicSharedMemorySize, LDS_BYTES);
    k_edge7<<<NBLK, NT, LDS_BYTES, stream>>>(csr, ea, xw1b, W1, W2, b2, out, E);
}